// Round 1
// baseline (2309.895 us; speedup 1.0000x reference)
//
#include <hip/hip_runtime.h>
#include <cstdint>
#include <cstddef>

#define H 128

// ---------------- utility kernels ----------------

__global__ void set_int_kernel(int* __restrict__ p, int n, int val) {
    int i = blockIdx.x * blockDim.x + threadIdx.x;
    if (i < n) p[i] = val;
}

__global__ void count_kernel(const int* __restrict__ dst, int E, int* __restrict__ cnt) {
    int e = blockIdx.x * blockDim.x + threadIdx.x;
    if (e < E) atomicAdd(&cnt[dst[e]], 1);
}

__global__ void dinv_kernel(const int* __restrict__ cnt, float* __restrict__ dinv, int n) {
    int i = blockIdx.x * blockDim.x + threadIdx.x;
    if (i < n) dinv[i] = rsqrtf((float)(cnt[i] + 1));  // +1 self-loop; deg >= 1 always
}

// single-block exclusive scan over n ints -> row_ptr[0..n]
__global__ __launch_bounds__(1024) void scan_kernel(const int* __restrict__ cnt,
                                                    int* __restrict__ row_ptr, int n) {
    __shared__ int sm[1024];
    __shared__ int carry;
    int tid = threadIdx.x;
    if (tid == 0) carry = 0;
    __syncthreads();
    for (int base = 0; base < n; base += 1024) {
        int i = base + tid;
        int v = (i < n) ? cnt[i] : 0;
        sm[tid] = v;
        __syncthreads();
        #pragma unroll
        for (int off = 1; off < 1024; off <<= 1) {
            int t = (tid >= off) ? sm[tid - off] : 0;
            __syncthreads();
            sm[tid] += t;
            __syncthreads();
        }
        int incl = sm[tid] + carry;
        if (i < n) row_ptr[i] = incl - v;  // exclusive
        __syncthreads();
        if (tid == 1023) carry = incl;
        __syncthreads();
    }
    if (tid == 0) row_ptr[n] = carry;
}

__global__ void fill_kernel(const int* __restrict__ src, const int* __restrict__ dst, int E,
                            const int* __restrict__ row_ptr, int* __restrict__ fill,
                            const float* __restrict__ dinv,
                            int* __restrict__ csr_src, float* __restrict__ csr_norm) {
    int e = blockIdx.x * blockDim.x + threadIdx.x;
    if (e < E) {
        int s = src[e], d = dst[e];
        int pos = atomicAdd(&fill[d], 1);
        int idx = row_ptr[d] + pos;
        csr_src[idx] = s;
        csr_norm[idx] = dinv[s] * dinv[d];
    }
}

__global__ void center_kernel(const int* __restrict__ batch, int n, int* __restrict__ center) {
    int i = blockIdx.x * blockDim.x + threadIdx.x;
    if (i < n) atomicMin(&center[batch[i]], i);
}

// ---------------- fp32 GEMM: Y[n,128] = X[n,128] @ W[128,128] ----------------
// BM=64 rows, BN=64 cols (blockIdx.y picks col half). 64 KB LDS -> 2 blocks/CU.
// GATHER: X row r comes from emb_table + z[r]*128 (fuses embedding lookup).

template<bool GATHER>
__global__ __launch_bounds__(256) void gemm_kernel(const float* __restrict__ X,
                                                   const int* __restrict__ z,
                                                   const float* __restrict__ Wm,
                                                   float* __restrict__ Y, int n) {
    __shared__ float Xs[64 * H];   // 32 KB
    __shared__ float Ws[H * 64];   // 32 KB
    int tid = threadIdx.x;
    int m0 = blockIdx.x * 64;
    int c0 = blockIdx.y * 64;

    // stage W cols [c0,c0+64): 128x64 floats = 2048 float4, 8 iters
    #pragma unroll
    for (int it = 0; it < 8; ++it) {
        int f  = it * 256 + tid;
        int r  = f >> 4;      // 16 float4 per row
        int c4 = f & 15;
        float4 v = *reinterpret_cast<const float4*>(Wm + r * H + c0 + c4 * 4);
        *reinterpret_cast<float4*>(Ws + r * 64 + c4 * 4) = v;
    }
    // stage X rows [m0,m0+64): 64x128 floats = 2048 float4, 8 iters
    #pragma unroll
    for (int it = 0; it < 8; ++it) {
        int f  = it * 256 + tid;
        int r  = f >> 5;      // 32 float4 per row
        int c4 = f & 31;
        int row = m0 + r;
        float4 v = make_float4(0.f, 0.f, 0.f, 0.f);
        if (row < n) {
            const float* sp = GATHER ? (X + (size_t)z[row] * H) : (X + (size_t)row * H);
            v = *reinterpret_cast<const float4*>(sp + c4 * 4);
        }
        *reinterpret_cast<float4*>(Xs + r * H + c4 * 4) = v;
    }
    __syncthreads();

    int tc = tid & 15;   // 16 col groups x 4 cols
    int tr = tid >> 4;   // 16 row groups x 4 rows
    int cc = tc * 4;
    int rr = tr * 4;
    float acc[4][4] = {};

    #pragma unroll
    for (int k = 0; k < H; k += 4) {
        float4 xv[4], wv[4];
        #pragma unroll
        for (int r = 0; r < 4; ++r)
            xv[r] = *reinterpret_cast<const float4*>(Xs + (rr + r) * H + k);
        #pragma unroll
        for (int kk = 0; kk < 4; ++kk)
            wv[kk] = *reinterpret_cast<const float4*>(Ws + (k + kk) * 64 + cc);
        #pragma unroll
        for (int kk = 0; kk < 4; ++kk) {
            float4 w = wv[kk];
            #pragma unroll
            for (int r = 0; r < 4; ++r) {
                float xs = (kk == 0) ? xv[r].x : (kk == 1) ? xv[r].y : (kk == 2) ? xv[r].z : xv[r].w;
                acc[r][0] = fmaf(xs, w.x, acc[r][0]);
                acc[r][1] = fmaf(xs, w.y, acc[r][1]);
                acc[r][2] = fmaf(xs, w.z, acc[r][2]);
                acc[r][3] = fmaf(xs, w.w, acc[r][3]);
            }
        }
    }

    #pragma unroll
    for (int r = 0; r < 4; ++r) {
        int row = m0 + rr + r;
        if (row < n) {
            float4 v = make_float4(acc[r][0], acc[r][1], acc[r][2], acc[r][3]);
            *reinterpret_cast<float4*>(Y + (size_t)row * H + c0 + cc) = v;
        }
    }
}

// ---------------- aggregation: Out[i] = b + sum_in h[src]*norm + h[i]*dinv^2 ----------------
// 2 nodes per 256-thread block, 1 thread per feature column.

template<bool RELU>
__global__ __launch_bounds__(256) void agg_kernel(const float* __restrict__ Hbuf,
                                                  const int* __restrict__ row_ptr,
                                                  const int* __restrict__ csr_src,
                                                  const float* __restrict__ csr_norm,
                                                  const float* __restrict__ dinv,
                                                  const float* __restrict__ bias,
                                                  float* __restrict__ Out, int n) {
    int node = blockIdx.x * 2 + (threadIdx.x >> 7);
    int c = threadIdx.x & 127;
    if (node >= n) return;
    float di = dinv[node];
    float acc = bias[c] + Hbuf[(size_t)node * H + c] * (di * di);
    int beg = row_ptr[node], end = row_ptr[node + 1];
    for (int j = beg; j < end; ++j) {
        int s = csr_src[j];
        float nm = csr_norm[j];
        acc = fmaf(Hbuf[(size_t)s * H + c], nm, acc);
    }
    if (RELU) acc = fmaxf(acc, 0.f);
    Out[(size_t)node * H + c] = acc;
}

// ---------------- readout: g = x[c]*x[c+1]; relu(g@W1+b1)@W2+b2 ----------------

__global__ __launch_bounds__(128) void readout_kernel(const float* __restrict__ X,
                                                      const int* __restrict__ center,
                                                      const float* __restrict__ w1,
                                                      const float* __restrict__ b1,
                                                      const float* __restrict__ w2,
                                                      const float* __restrict__ b2,
                                                      float* __restrict__ out, int n) {
    __shared__ float gv[H];
    __shared__ float red[H];
    int g = blockIdx.x;
    int c = threadIdx.x;
    int i0 = center[g];
    if (i0 > n - 1) i0 = n - 1;
    int i1 = (i0 + 1 < n) ? i0 + 1 : n - 1;
    gv[c] = X[(size_t)i0 * H + c] * X[(size_t)i1 * H + c];
    __syncthreads();
    float acc = b1[c];
    #pragma unroll 8
    for (int k = 0; k < H; ++k)
        acc = fmaf(gv[k], w1[k * H + c], acc);
    acc = fmaxf(acc, 0.f);
    red[c] = acc * w2[c];
    __syncthreads();
    for (int off = 64; off > 0; off >>= 1) {
        if (c < off) red[c] += red[c + off];
        __syncthreads();
    }
    if (c == 0) out[g] = red[0] + b2[0];
}

// ---------------- launcher ----------------

static inline size_t align_up(size_t x) { return (x + 255) & ~(size_t)255; }

extern "C" void kernel_launch(void* const* d_in, const int* in_sizes, int n_in,
                              void* d_out, int out_size, void* d_ws, size_t ws_size,
                              hipStream_t stream) {
    const int n = in_sizes[0];
    const int E = in_sizes[1] / 2;
    const int G = out_size;  // output is [G,1]

    const int*   z      = (const int*)d_in[0];
    const int*   ei     = (const int*)d_in[1];
    const int*   batch  = (const int*)d_in[2];
    const float* emb    = (const float*)d_in[4];
    const float* w0     = (const float*)d_in[5];
    const float* b0     = (const float*)d_in[6];
    const float* w1     = (const float*)d_in[7];
    const float* b1     = (const float*)d_in[8];
    const float* w2     = (const float*)d_in[9];
    const float* b2     = (const float*)d_in[10];
    const float* lin1_w = (const float*)d_in[11];
    const float* lin1_b = (const float*)d_in[12];
    const float* lin2_w = (const float*)d_in[13];
    const float* lin2_b = (const float*)d_in[14];

    const int* e_src = ei;
    const int* e_dst = ei + E;

    char* p = (char*)d_ws;
    int*   cnt      = (int*)p;  p += align_up((size_t)n * 4);
    int*   row_ptr  = (int*)p;  p += align_up((size_t)(n + 1) * 4);
    int*   fill     = (int*)p;  p += align_up((size_t)n * 4);
    int*   center   = (int*)p;  p += align_up((size_t)G * 4);
    int*   csr_src  = (int*)p;  p += align_up((size_t)E * 4);
    float* dinv     = (float*)p; p += align_up((size_t)n * 4);
    float* csr_norm = (float*)p; p += align_up((size_t)E * 4);
    float* bufA     = (float*)p; p += align_up((size_t)n * H * 4);
    float* bufB     = (float*)p; p += align_up((size_t)n * H * 4);

    const int TB = 256;
    dim3 gN((n + TB - 1) / TB);
    dim3 gE((E + TB - 1) / TB);
    dim3 gG((G + TB - 1) / TB);

    // build degree / dinv / CSR
    set_int_kernel<<<gN, TB, 0, stream>>>(cnt, n, 0);
    set_int_kernel<<<gN, TB, 0, stream>>>(fill, n, 0);
    set_int_kernel<<<gG, TB, 0, stream>>>(center, G, 0x7fffffff);
    count_kernel<<<gE, TB, 0, stream>>>(e_dst, E, cnt);
    dinv_kernel<<<gN, TB, 0, stream>>>(cnt, dinv, n);
    scan_kernel<<<1, 1024, 0, stream>>>(cnt, row_ptr, n);
    fill_kernel<<<gE, TB, 0, stream>>>(e_src, e_dst, E, row_ptr, fill, dinv, csr_src, csr_norm);
    center_kernel<<<gN, TB, 0, stream>>>(batch, n, center);

    dim3 gemm_grid((n + 63) / 64, 2);
    dim3 agg_grid((n + 1) / 2);

    // layer 0 (embedding gather fused into GEMM staging)
    gemm_kernel<true><<<gemm_grid, 256, 0, stream>>>(emb, z, w0, bufB, n);
    agg_kernel<true><<<agg_grid, 256, 0, stream>>>(bufB, row_ptr, csr_src, csr_norm, dinv, b0, bufA, n);
    // layer 1
    gemm_kernel<false><<<gemm_grid, 256, 0, stream>>>(bufA, nullptr, w1, bufB, n);
    agg_kernel<true><<<agg_grid, 256, 0, stream>>>(bufB, row_ptr, csr_src, csr_norm, dinv, b1, bufA, n);
    // layer 2 (no relu)
    gemm_kernel<false><<<gemm_grid, 256, 0, stream>>>(bufA, nullptr, w2, bufB, n);
    agg_kernel<false><<<agg_grid, 256, 0, stream>>>(bufB, row_ptr, csr_src, csr_norm, dinv, b2, bufA, n);

    // readout
    readout_kernel<<<G, 128, 0, stream>>>(bufA, center, lin1_w, lin1_b, lin2_w, lin2_b,
                                          (float*)d_out, n);
}

// Round 3
// 503.473 us; speedup vs baseline: 4.5879x; 4.5879x over previous
//
#include <hip/hip_runtime.h>
#include <cstdint>
#include <cstddef>

#define H 128
#define XS_LD 132   // padded LDS stride for X tile (breaks 512B bank aliasing)

// ---------------- utility kernels ----------------

__global__ void set_int_kernel(int* __restrict__ p, int n, int val) {
    int i = blockIdx.x * blockDim.x + threadIdx.x;
    if (i < n) p[i] = val;
}

__global__ void count_kernel(const int* __restrict__ dst, int E, int* __restrict__ cnt) {
    int e = blockIdx.x * blockDim.x + threadIdx.x;
    if (e < E) atomicAdd(&cnt[dst[e]], 1);
}

__global__ void dinv_kernel(const int* __restrict__ cnt, float* __restrict__ dinv, int n) {
    int i = blockIdx.x * blockDim.x + threadIdx.x;
    if (i < n) dinv[i] = rsqrtf((float)(cnt[i] + 1));  // +1 self-loop; deg >= 1 always
}

// single-block exclusive scan over n ints -> row_ptr[0..n]
__global__ __launch_bounds__(1024) void scan_kernel(const int* __restrict__ cnt,
                                                    int* __restrict__ row_ptr, int n) {
    __shared__ int sm[1024];
    __shared__ int carry;
    int tid = threadIdx.x;
    if (tid == 0) carry = 0;
    __syncthreads();
    for (int base = 0; base < n; base += 1024) {
        int i = base + tid;
        int v = (i < n) ? cnt[i] : 0;
        sm[tid] = v;
        __syncthreads();
        #pragma unroll
        for (int off = 1; off < 1024; off <<= 1) {
            int t = (tid >= off) ? sm[tid - off] : 0;
            __syncthreads();
            sm[tid] += t;
            __syncthreads();
        }
        int incl = sm[tid] + carry;
        if (i < n) row_ptr[i] = incl - v;  // exclusive
        __syncthreads();
        if (tid == 1023) carry = incl;
        __syncthreads();
    }
    if (tid == 0) row_ptr[n] = carry;
}

__global__ void fill_kernel(const int* __restrict__ src, const int* __restrict__ dst, int E,
                            const int* __restrict__ row_ptr, int* __restrict__ fill,
                            const float* __restrict__ dinv,
                            int* __restrict__ csr_src, float* __restrict__ csr_norm) {
    int e = blockIdx.x * blockDim.x + threadIdx.x;
    if (e < E) {
        int s = src[e], d = dst[e];
        int pos = atomicAdd(&fill[d], 1);
        int idx = row_ptr[d] + pos;
        csr_src[idx] = s;
        csr_norm[idx] = dinv[s] * dinv[d];
    }
}

__global__ void center_kernel(const int* __restrict__ batch, int n, int* __restrict__ center) {
    int i = blockIdx.x * blockDim.x + threadIdx.x;
    if (i < n) atomicMin(&center[batch[i]], i);
}

// ---------------- fp32 GEMM: Y[n,128] = X[n,128] @ W[128,128] ----------------
// BM=64 rows, BN=64 cols (blockIdx.y picks col half). LDS 66.5 KB -> 2 blocks/CU.
// GATHER: X row r comes from emb_table + z[r]*128 (fuses embedding lookup).
// __launch_bounds__(256,2) caps VGPRs at 128; #pragma unroll 2 keeps live set small.

template<bool GATHER>
__global__ __launch_bounds__(256, 2) void gemm_kernel(const float* __restrict__ X,
                                                      const int* __restrict__ z,
                                                      const float* __restrict__ Wm,
                                                      float* __restrict__ Y, int n) {
    __shared__ float Xs[64 * XS_LD];   // 33.8 KB
    __shared__ float Ws[H * 64];       // 32 KB
    int tid = threadIdx.x;
    int m0 = blockIdx.x * 64;
    int c0 = blockIdx.y * 64;

    // stage W cols [c0,c0+64): 128x64 floats = 2048 float4, 8 iters
    #pragma unroll
    for (int it = 0; it < 8; ++it) {
        int f  = it * 256 + tid;
        int r  = f >> 4;      // 16 float4 per row
        int c4 = f & 15;
        float4 v = *reinterpret_cast<const float4*>(Wm + r * H + c0 + c4 * 4);
        *reinterpret_cast<float4*>(Ws + r * 64 + c4 * 4) = v;
    }
    // stage X rows [m0,m0+64): 64x128 floats = 2048 float4, 8 iters
    #pragma unroll
    for (int it = 0; it < 8; ++it) {
        int f  = it * 256 + tid;
        int r  = f >> 5;      // 32 float4 per row
        int c4 = f & 31;
        int row = m0 + r;
        float4 v = make_float4(0.f, 0.f, 0.f, 0.f);
        if (row < n) {
            const float* sp = GATHER ? (X + (size_t)z[row] * H) : (X + (size_t)row * H);
            v = *reinterpret_cast<const float4*>(sp + c4 * 4);
        }
        *reinterpret_cast<float4*>(Xs + r * XS_LD + c4 * 4) = v;
    }
    __syncthreads();

    int tc = tid & 15;   // 16 col groups x 4 cols
    int tr = tid >> 4;   // 16 row groups x 4 rows
    int cc = tc * 4;
    int rr = tr * 4;
    float acc[4][4] = {};

    #pragma unroll 2
    for (int k = 0; k < H; k += 4) {
        float4 xv[4], wv[4];
        #pragma unroll
        for (int r = 0; r < 4; ++r)
            xv[r] = *reinterpret_cast<const float4*>(Xs + (rr + r) * XS_LD + k);
        #pragma unroll
        for (int kk = 0; kk < 4; ++kk)
            wv[kk] = *reinterpret_cast<const float4*>(Ws + (k + kk) * 64 + cc);
        #pragma unroll
        for (int kk = 0; kk < 4; ++kk) {
            float4 w = wv[kk];
            #pragma unroll
            for (int r = 0; r < 4; ++r) {
                float xs = (kk == 0) ? xv[r].x : (kk == 1) ? xv[r].y : (kk == 2) ? xv[r].z : xv[r].w;
                acc[r][0] = fmaf(xs, w.x, acc[r][0]);
                acc[r][1] = fmaf(xs, w.y, acc[r][1]);
                acc[r][2] = fmaf(xs, w.z, acc[r][2]);
                acc[r][3] = fmaf(xs, w.w, acc[r][3]);
            }
        }
    }

    #pragma unroll
    for (int r = 0; r < 4; ++r) {
        int row = m0 + rr + r;
        if (row < n) {
            float4 v = make_float4(acc[r][0], acc[r][1], acc[r][2], acc[r][3]);
            *reinterpret_cast<float4*>(Y + (size_t)row * H + c0 + cc) = v;
        }
    }
}

// ---------------- aggregation: Out[i] = b + sum_in h[src]*norm + h[i]*dinv^2 ----------------
// 8 nodes per 256-thread block; 32 lanes per node, one float4 per lane.

template<bool RELU>
__global__ __launch_bounds__(256) void agg_kernel(const float* __restrict__ Hbuf,
                                                  const int* __restrict__ row_ptr,
                                                  const int* __restrict__ csr_src,
                                                  const float* __restrict__ csr_norm,
                                                  const float* __restrict__ dinv,
                                                  const float* __restrict__ bias,
                                                  float* __restrict__ Out, int n) {
    int node = blockIdx.x * 8 + (threadIdx.x >> 5);
    int lane = threadIdx.x & 31;          // 32 float4 per 128-float row
    if (node >= n) return;
    const float4* Hb = reinterpret_cast<const float4*>(Hbuf);
    float di = dinv[node];
    float s = di * di;
    float4 x  = Hb[(size_t)node * 32 + lane];
    float4 bv = reinterpret_cast<const float4*>(bias)[lane];
    float4 acc = make_float4(bv.x + x.x * s, bv.y + x.y * s,
                             bv.z + x.z * s, bv.w + x.w * s);
    int beg = row_ptr[node], end = row_ptr[node + 1];
    for (int j = beg; j < end; ++j) {
        int sN = csr_src[j];
        float nm = csr_norm[j];
        float4 hv = Hb[(size_t)sN * 32 + lane];
        acc.x = fmaf(hv.x, nm, acc.x);
        acc.y = fmaf(hv.y, nm, acc.y);
        acc.z = fmaf(hv.z, nm, acc.z);
        acc.w = fmaf(hv.w, nm, acc.w);
    }
    if (RELU) {
        acc.x = fmaxf(acc.x, 0.f); acc.y = fmaxf(acc.y, 0.f);
        acc.z = fmaxf(acc.z, 0.f); acc.w = fmaxf(acc.w, 0.f);
    }
    reinterpret_cast<float4*>(Out)[(size_t)node * 32 + lane] = acc;
}

// ---------------- readout: g = x[c]*x[c+1]; relu(g@W1+b1)@W2+b2 ----------------

__global__ __launch_bounds__(128) void readout_kernel(const float* __restrict__ X,
                                                      const int* __restrict__ center,
                                                      const float* __restrict__ w1,
                                                      const float* __restrict__ b1,
                                                      const float* __restrict__ w2,
                                                      const float* __restrict__ b2,
                                                      float* __restrict__ out, int n) {
    __shared__ float gv[H];
    __shared__ float red[H];
    int g = blockIdx.x;
    int c = threadIdx.x;
    int i0 = center[g];
    if (i0 > n - 1) i0 = n - 1;
    int i1 = (i0 + 1 < n) ? i0 + 1 : n - 1;
    gv[c] = X[(size_t)i0 * H + c] * X[(size_t)i1 * H + c];
    __syncthreads();
    float acc = b1[c];
    #pragma unroll 8
    for (int k = 0; k < H; ++k)
        acc = fmaf(gv[k], w1[k * H + c], acc);
    acc = fmaxf(acc, 0.f);
    red[c] = acc * w2[c];
    __syncthreads();
    for (int off = 64; off > 0; off >>= 1) {
        if (c < off) red[c] += red[c + off];
        __syncthreads();
    }
    if (c == 0) out[g] = red[0] + b2[0];
}

// ---------------- launcher ----------------

static inline size_t align_up(size_t x) { return (x + 255) & ~(size_t)255; }

extern "C" void kernel_launch(void* const* d_in, const int* in_sizes, int n_in,
                              void* d_out, int out_size, void* d_ws, size_t ws_size,
                              hipStream_t stream) {
    const int n = in_sizes[0];
    const int E = in_sizes[1] / 2;
    const int G = out_size;  // output is [G,1]

    const int*   z      = (const int*)d_in[0];
    const int*   ei     = (const int*)d_in[1];
    const int*   batch  = (const int*)d_in[2];
    const float* emb    = (const float*)d_in[4];
    const float* w0     = (const float*)d_in[5];
    const float* b0     = (const float*)d_in[6];
    const float* w1     = (const float*)d_in[7];
    const float* b1     = (const float*)d_in[8];
    const float* w2     = (const float*)d_in[9];
    const float* b2     = (const float*)d_in[10];
    const float* lin1_w = (const float*)d_in[11];
    const float* lin1_b = (const float*)d_in[12];
    const float* lin2_w = (const float*)d_in[13];
    const float* lin2_b = (const float*)d_in[14];

    const int* e_src = ei;
    const int* e_dst = ei + E;

    char* p = (char*)d_ws;
    int*   cnt      = (int*)p;  p += align_up((size_t)n * 4);
    int*   row_ptr  = (int*)p;  p += align_up((size_t)(n + 1) * 4);
    int*   fill     = (int*)p;  p += align_up((size_t)n * 4);
    int*   center   = (int*)p;  p += align_up((size_t)G * 4);
    int*   csr_src  = (int*)p;  p += align_up((size_t)E * 4);
    float* dinv     = (float*)p; p += align_up((size_t)n * 4);
    float* csr_norm = (float*)p; p += align_up((size_t)E * 4);
    float* bufA     = (float*)p; p += align_up((size_t)n * H * 4);
    float* bufB     = (float*)p; p += align_up((size_t)n * H * 4);

    const int TB = 256;
    dim3 gN((n + TB - 1) / TB);
    dim3 gE((E + TB - 1) / TB);
    dim3 gG((G + TB - 1) / TB);

    // build degree / dinv / CSR
    set_int_kernel<<<gN, TB, 0, stream>>>(cnt, n, 0);
    set_int_kernel<<<gN, TB, 0, stream>>>(fill, n, 0);
    set_int_kernel<<<gG, TB, 0, stream>>>(center, G, 0x7fffffff);
    count_kernel<<<gE, TB, 0, stream>>>(e_dst, E, cnt);
    dinv_kernel<<<gN, TB, 0, stream>>>(cnt, dinv, n);
    scan_kernel<<<1, 1024, 0, stream>>>(cnt, row_ptr, n);
    fill_kernel<<<gE, TB, 0, stream>>>(e_src, e_dst, E, row_ptr, fill, dinv, csr_src, csr_norm);
    center_kernel<<<gN, TB, 0, stream>>>(batch, n, center);

    dim3 gemm_grid((n + 63) / 64, 2);
    dim3 agg_grid((n + 7) / 8);

    // layer 0 (embedding gather fused into GEMM staging)
    gemm_kernel<true><<<gemm_grid, 256, 0, stream>>>(emb, z, w0, bufB, n);
    agg_kernel<true><<<agg_grid, 256, 0, stream>>>(bufB, row_ptr, csr_src, csr_norm, dinv, b0, bufA, n);
    // layer 1
    gemm_kernel<false><<<gemm_grid, 256, 0, stream>>>(bufA, nullptr, w1, bufB, n);
    agg_kernel<true><<<agg_grid, 256, 0, stream>>>(bufB, row_ptr, csr_src, csr_norm, dinv, b1, bufA, n);
    // layer 2 (no relu)
    gemm_kernel<false><<<gemm_grid, 256, 0, stream>>>(bufA, nullptr, w2, bufB, n);
    agg_kernel<false><<<agg_grid, 256, 0, stream>>>(bufB, row_ptr, csr_src, csr_norm, dinv, b2, bufA, n);

    // readout
    readout_kernel<<<G, 128, 0, stream>>>(bufA, center, lin1_w, lin1_b, lin2_w, lin2_b,
                                          (float*)d_out, n);
}

// Round 4
// 424.661 us; speedup vs baseline: 5.4394x; 1.1856x over previous
//
#include <hip/hip_runtime.h>
#include <cstdint>
#include <cstddef>

#define H 128
#define XS_LD 132   // padded LDS stride for X tile (breaks 512B bank aliasing)
#define SCAN_CHUNK 2048   // elements per scan_local block (256 thr x 8)

// ---------------- utility kernels ----------------

__global__ void set_int_kernel(int* __restrict__ p, int n, int val) {
    int i = blockIdx.x * blockDim.x + threadIdx.x;
    if (i < n) p[i] = val;
}

__global__ void count_kernel(const int* __restrict__ dst, int E, int* __restrict__ cnt) {
    int e = blockIdx.x * blockDim.x + threadIdx.x;
    if (e < E) atomicAdd(&cnt[dst[e]], 1);
}

// per-block exclusive scan of cnt into row_ptr; block totals -> partials.
// Also computes dinv[i] = rsqrt(cnt[i]+1) (self-loop degree) for free.
__global__ __launch_bounds__(256) void scan_local(const int* __restrict__ cnt,
                                                  int* __restrict__ row_ptr,
                                                  int* __restrict__ partials,
                                                  float* __restrict__ dinv, int n) {
    __shared__ int sm[256];
    int tid = threadIdx.x;
    int base = blockIdx.x * SCAN_CHUNK + tid * 8;
    int v[8];
    int s = 0;
    #pragma unroll
    for (int j = 0; j < 8; ++j) {
        int i = base + j;
        v[j] = (i < n) ? cnt[i] : 0;
        if (i < n) dinv[i] = rsqrtf((float)(v[j] + 1));
        s += v[j];
    }
    sm[tid] = s;
    __syncthreads();
    #pragma unroll
    for (int off = 1; off < 256; off <<= 1) {
        int t = (tid >= off) ? sm[tid - off] : 0;
        __syncthreads();
        sm[tid] += t;
        __syncthreads();
    }
    int excl = sm[tid] - s;   // exclusive prefix within block
    if (tid == 255) partials[blockIdx.x] = sm[255];
    #pragma unroll
    for (int j = 0; j < 8; ++j) {
        int i = base + j;
        if (i < n) row_ptr[i] = excl;
        excl += v[j];
    }
}

// single-wave scan of block partials (nPart <= 64); writes row_ptr[n] = total.
__global__ __launch_bounds__(64) void scan_partials(int* __restrict__ partials,
                                                    int* __restrict__ row_ptr,
                                                    int nPart, int n) {
    int tid = threadIdx.x;
    int v = (tid < nPart) ? partials[tid] : 0;
    int ps = v;
    #pragma unroll
    for (int off = 1; off < 64; off <<= 1) {
        int t = __shfl_up(ps, off);
        if (tid >= off) ps += t;
    }
    if (tid < nPart) partials[tid] = ps - v;  // exclusive
    if (tid == 63) row_ptr[n] = ps;           // total edge count
}

__global__ void scan_add(int* __restrict__ row_ptr, const int* __restrict__ partials, int n) {
    int i = blockIdx.x * blockDim.x + threadIdx.x;
    if (i < n) row_ptr[i] += partials[i / SCAN_CHUNK];
}

__global__ void fill_kernel(const int* __restrict__ src, const int* __restrict__ dst, int E,
                            const int* __restrict__ row_ptr, int* __restrict__ fill,
                            const float* __restrict__ dinv,
                            int* __restrict__ csr_src, float* __restrict__ csr_norm) {
    int e = blockIdx.x * blockDim.x + threadIdx.x;
    if (e < E) {
        int s = src[e], d = dst[e];
        int pos = atomicAdd(&fill[d], 1);
        int idx = row_ptr[d] + pos;
        csr_src[idx] = s;
        csr_norm[idx] = dinv[s] * dinv[d];
    }
}

__global__ void center_kernel(const int* __restrict__ batch, int n, int* __restrict__ center) {
    int i = blockIdx.x * blockDim.x + threadIdx.x;
    if (i < n) atomicMin(&center[batch[i]], i);
}

// ---------------- fp32 GEMM: Y[n,128] = X[n,128] @ W[128,128] ----------------
// BM=64 rows, BN=64 cols (blockIdx.y picks col half). LDS 66.5 KB -> 2 blocks/CU.
// GATHER: X row r comes from emb_table + z[r]*128 (fuses embedding lookup).
// __launch_bounds__(256,2) caps VGPRs at 128; #pragma unroll 2 keeps live set small.

template<bool GATHER>
__global__ __launch_bounds__(256, 2) void gemm_kernel(const float* __restrict__ X,
                                                      const int* __restrict__ z,
                                                      const float* __restrict__ Wm,
                                                      float* __restrict__ Y, int n) {
    __shared__ float Xs[64 * XS_LD];   // 33.8 KB
    __shared__ float Ws[H * 64];       // 32 KB
    int tid = threadIdx.x;
    int m0 = blockIdx.x * 64;
    int c0 = blockIdx.y * 64;

    // stage W cols [c0,c0+64): 128x64 floats = 2048 float4, 8 iters
    #pragma unroll
    for (int it = 0; it < 8; ++it) {
        int f  = it * 256 + tid;
        int r  = f >> 4;      // 16 float4 per row
        int c4 = f & 15;
        float4 v = *reinterpret_cast<const float4*>(Wm + r * H + c0 + c4 * 4);
        *reinterpret_cast<float4*>(Ws + r * 64 + c4 * 4) = v;
    }
    // stage X rows [m0,m0+64): 64x128 floats = 2048 float4, 8 iters
    #pragma unroll
    for (int it = 0; it < 8; ++it) {
        int f  = it * 256 + tid;
        int r  = f >> 5;      // 32 float4 per row
        int c4 = f & 31;
        int row = m0 + r;
        float4 v = make_float4(0.f, 0.f, 0.f, 0.f);
        if (row < n) {
            const float* sp = GATHER ? (X + (size_t)z[row] * H) : (X + (size_t)row * H);
            v = *reinterpret_cast<const float4*>(sp + c4 * 4);
        }
        *reinterpret_cast<float4*>(Xs + r * XS_LD + c4 * 4) = v;
    }
    __syncthreads();

    int tc = tid & 15;   // 16 col groups x 4 cols
    int tr = tid >> 4;   // 16 row groups x 4 rows
    int cc = tc * 4;
    int rr = tr * 4;
    float acc[4][4] = {};

    #pragma unroll 2
    for (int k = 0; k < H; k += 4) {
        float4 xv[4], wv[4];
        #pragma unroll
        for (int r = 0; r < 4; ++r)
            xv[r] = *reinterpret_cast<const float4*>(Xs + (rr + r) * XS_LD + k);
        #pragma unroll
        for (int kk = 0; kk < 4; ++kk)
            wv[kk] = *reinterpret_cast<const float4*>(Ws + (k + kk) * 64 + cc);
        #pragma unroll
        for (int kk = 0; kk < 4; ++kk) {
            float4 w = wv[kk];
            #pragma unroll
            for (int r = 0; r < 4; ++r) {
                float xs = (kk == 0) ? xv[r].x : (kk == 1) ? xv[r].y : (kk == 2) ? xv[r].z : xv[r].w;
                acc[r][0] = fmaf(xs, w.x, acc[r][0]);
                acc[r][1] = fmaf(xs, w.y, acc[r][1]);
                acc[r][2] = fmaf(xs, w.z, acc[r][2]);
                acc[r][3] = fmaf(xs, w.w, acc[r][3]);
            }
        }
    }

    #pragma unroll
    for (int r = 0; r < 4; ++r) {
        int row = m0 + rr + r;
        if (row < n) {
            float4 v = make_float4(acc[r][0], acc[r][1], acc[r][2], acc[r][3]);
            *reinterpret_cast<float4*>(Y + (size_t)row * H + c0 + cc) = v;
        }
    }
}

// ---------------- aggregation: Out[i] = b + sum_in h[src]*norm + h[i]*dinv^2 ----------------
// 8 nodes per 256-thread block; 32 lanes per node, one float4 per lane.

template<bool RELU>
__global__ __launch_bounds__(256) void agg_kernel(const float* __restrict__ Hbuf,
                                                  const int* __restrict__ row_ptr,
                                                  const int* __restrict__ csr_src,
                                                  const float* __restrict__ csr_norm,
                                                  const float* __restrict__ dinv,
                                                  const float* __restrict__ bias,
                                                  float* __restrict__ Out, int n) {
    int node = blockIdx.x * 8 + (threadIdx.x >> 5);
    int lane = threadIdx.x & 31;          // 32 float4 per 128-float row
    if (node >= n) return;
    const float4* Hb = reinterpret_cast<const float4*>(Hbuf);
    float di = dinv[node];
    float s = di * di;
    float4 x  = Hb[(size_t)node * 32 + lane];
    float4 bv = reinterpret_cast<const float4*>(bias)[lane];
    float4 acc = make_float4(bv.x + x.x * s, bv.y + x.y * s,
                             bv.z + x.z * s, bv.w + x.w * s);
    int beg = row_ptr[node], end = row_ptr[node + 1];
    for (int j = beg; j < end; ++j) {
        int sN = csr_src[j];
        float nm = csr_norm[j];
        float4 hv = Hb[(size_t)sN * 32 + lane];
        acc.x = fmaf(hv.x, nm, acc.x);
        acc.y = fmaf(hv.y, nm, acc.y);
        acc.z = fmaf(hv.z, nm, acc.z);
        acc.w = fmaf(hv.w, nm, acc.w);
    }
    if (RELU) {
        acc.x = fmaxf(acc.x, 0.f); acc.y = fmaxf(acc.y, 0.f);
        acc.z = fmaxf(acc.z, 0.f); acc.w = fmaxf(acc.w, 0.f);
    }
    reinterpret_cast<float4*>(Out)[(size_t)node * 32 + lane] = acc;
}

// ---------------- readout: g = x[c]*x[c+1]; relu(g@W1+b1)@W2+b2 ----------------

__global__ __launch_bounds__(128) void readout_kernel(const float* __restrict__ X,
                                                      const int* __restrict__ center,
                                                      const float* __restrict__ w1,
                                                      const float* __restrict__ b1,
                                                      const float* __restrict__ w2,
                                                      const float* __restrict__ b2,
                                                      float* __restrict__ out, int n) {
    __shared__ float gv[H];
    __shared__ float red[H];
    int g = blockIdx.x;
    int c = threadIdx.x;
    int i0 = center[g];
    if (i0 > n - 1) i0 = n - 1;
    int i1 = (i0 + 1 < n) ? i0 + 1 : n - 1;
    gv[c] = X[(size_t)i0 * H + c] * X[(size_t)i1 * H + c];
    __syncthreads();
    float acc = b1[c];
    #pragma unroll 8
    for (int k = 0; k < H; ++k)
        acc = fmaf(gv[k], w1[k * H + c], acc);
    acc = fmaxf(acc, 0.f);
    red[c] = acc * w2[c];
    __syncthreads();
    for (int off = 64; off > 0; off >>= 1) {
        if (c < off) red[c] += red[c + off];
        __syncthreads();
    }
    if (c == 0) out[g] = red[0] + b2[0];
}

// ---------------- launcher ----------------

static inline size_t align_up(size_t x) { return (x + 255) & ~(size_t)255; }

extern "C" void kernel_launch(void* const* d_in, const int* in_sizes, int n_in,
                              void* d_out, int out_size, void* d_ws, size_t ws_size,
                              hipStream_t stream) {
    const int n = in_sizes[0];
    const int E = in_sizes[1] / 2;
    const int G = out_size;  // output is [G,1]

    const int*   z      = (const int*)d_in[0];
    const int*   ei     = (const int*)d_in[1];
    const int*   batch  = (const int*)d_in[2];
    const float* emb    = (const float*)d_in[4];
    const float* w0     = (const float*)d_in[5];
    const float* b0     = (const float*)d_in[6];
    const float* w1     = (const float*)d_in[7];
    const float* b1     = (const float*)d_in[8];
    const float* w2     = (const float*)d_in[9];
    const float* b2     = (const float*)d_in[10];
    const float* lin1_w = (const float*)d_in[11];
    const float* lin1_b = (const float*)d_in[12];
    const float* lin2_w = (const float*)d_in[13];
    const float* lin2_b = (const float*)d_in[14];

    const int* e_src = ei;
    const int* e_dst = ei + E;

    const int nPart = (n + SCAN_CHUNK - 1) / SCAN_CHUNK;  // 25 for n=50000 (<=64 required)

    char* p = (char*)d_ws;
    int*   cnt      = (int*)p;  p += align_up((size_t)n * 4);
    int*   row_ptr  = (int*)p;  p += align_up((size_t)(n + 1) * 4);
    int*   fill     = (int*)p;  p += align_up((size_t)n * 4);
    int*   center   = (int*)p;  p += align_up((size_t)G * 4);
    int*   partials = (int*)p;  p += align_up((size_t)64 * 4);
    int*   csr_src  = (int*)p;  p += align_up((size_t)E * 4);
    float* dinv     = (float*)p; p += align_up((size_t)n * 4);
    float* csr_norm = (float*)p; p += align_up((size_t)E * 4);
    float* bufA     = (float*)p; p += align_up((size_t)n * H * 4);
    float* bufB     = (float*)p; p += align_up((size_t)n * H * 4);

    const int TB = 256;
    dim3 gN((n + TB - 1) / TB);
    dim3 gE((E + TB - 1) / TB);
    dim3 gG((G + TB - 1) / TB);

    // build degree / dinv / CSR
    set_int_kernel<<<gN, TB, 0, stream>>>(cnt, n, 0);
    set_int_kernel<<<gN, TB, 0, stream>>>(fill, n, 0);
    set_int_kernel<<<gG, TB, 0, stream>>>(center, G, 0x7fffffff);
    count_kernel<<<gE, TB, 0, stream>>>(e_dst, E, cnt);
    scan_local<<<nPart, 256, 0, stream>>>(cnt, row_ptr, partials, dinv, n);
    scan_partials<<<1, 64, 0, stream>>>(partials, row_ptr, nPart, n);
    scan_add<<<gN, TB, 0, stream>>>(row_ptr, partials, n);
    fill_kernel<<<gE, TB, 0, stream>>>(e_src, e_dst, E, row_ptr, fill, dinv, csr_src, csr_norm);
    center_kernel<<<gN, TB, 0, stream>>>(batch, n, center);

    dim3 gemm_grid((n + 63) / 64, 2);
    dim3 agg_grid((n + 7) / 8);

    // layer 0 (embedding gather fused into GEMM staging)
    gemm_kernel<true><<<gemm_grid, 256, 0, stream>>>(emb, z, w0, bufB, n);
    agg_kernel<true><<<agg_grid, 256, 0, stream>>>(bufB, row_ptr, csr_src, csr_norm, dinv, b0, bufA, n);
    // layer 1
    gemm_kernel<false><<<gemm_grid, 256, 0, stream>>>(bufA, nullptr, w1, bufB, n);
    agg_kernel<true><<<agg_grid, 256, 0, stream>>>(bufB, row_ptr, csr_src, csr_norm, dinv, b1, bufA, n);
    // layer 2 (no relu)
    gemm_kernel<false><<<gemm_grid, 256, 0, stream>>>(bufA, nullptr, w2, bufB, n);
    agg_kernel<false><<<agg_grid, 256, 0, stream>>>(bufB, row_ptr, csr_src, csr_norm, dinv, b2, bufA, n);

    // readout
    readout_kernel<<<G, 128, 0, stream>>>(bufA, center, lin1_w, lin1_b, lin2_w, lin2_b,
                                          (float*)d_out, n);
}

// Round 8
// 398.330 us; speedup vs baseline: 5.7989x; 1.0661x over previous
//
#include <hip/hip_runtime.h>
#include <cstdint>
#include <cstddef>

#define H 128
#define XS_LD 132   // padded LDS stride for X tile (breaks 512B bank aliasing)
#define SCAN_CHUNK 2048   // elements per scan_local block (256 thr x 8)

// ---------------- utility kernels ----------------

__global__ void set_int_kernel(int* __restrict__ p, int n, int val) {
    int i = blockIdx.x * blockDim.x + threadIdx.x;
    if (i < n) p[i] = val;
}

__global__ void count_kernel(const int* __restrict__ dst, int E, int* __restrict__ cnt) {
    int e = blockIdx.x * blockDim.x + threadIdx.x;
    if (e < E) atomicAdd(&cnt[dst[e]], 1);
}

// per-block exclusive scan of cnt into row_ptr; block totals -> partials.
// Also computes dinv[i] = rsqrt(cnt[i]+1) (self-loop degree) for free.
__global__ __launch_bounds__(256) void scan_local(const int* __restrict__ cnt,
                                                  int* __restrict__ row_ptr,
                                                  int* __restrict__ partials,
                                                  float* __restrict__ dinv, int n) {
    __shared__ int sm[256];
    int tid = threadIdx.x;
    int base = blockIdx.x * SCAN_CHUNK + tid * 8;
    int v[8];
    int s = 0;
    #pragma unroll
    for (int j = 0; j < 8; ++j) {
        int i = base + j;
        v[j] = (i < n) ? cnt[i] : 0;
        if (i < n) dinv[i] = rsqrtf((float)(v[j] + 1));
        s += v[j];
    }
    sm[tid] = s;
    __syncthreads();
    #pragma unroll
    for (int off = 1; off < 256; off <<= 1) {
        int t = (tid >= off) ? sm[tid - off] : 0;
        __syncthreads();
        sm[tid] += t;
        __syncthreads();
    }
    int excl = sm[tid] - s;   // exclusive prefix within block
    if (tid == 255) partials[blockIdx.x] = sm[255];
    #pragma unroll
    for (int j = 0; j < 8; ++j) {
        int i = base + j;
        if (i < n) row_ptr[i] = excl;
        excl += v[j];
    }
}

// single-wave scan of block partials (nPart <= 64); writes row_ptr[n] = total.
__global__ __launch_bounds__(64) void scan_partials(int* __restrict__ partials,
                                                    int* __restrict__ row_ptr,
                                                    int nPart, int n) {
    int tid = threadIdx.x;
    int v = (tid < nPart) ? partials[tid] : 0;
    int ps = v;
    #pragma unroll
    for (int off = 1; off < 64; off <<= 1) {
        int t = __shfl_up(ps, off);
        if (tid >= off) ps += t;
    }
    if (tid < nPart) partials[tid] = ps - v;  // exclusive
    if (tid == 63) row_ptr[n] = ps;           // total edge count
}

__global__ void scan_add(int* __restrict__ row_ptr, const int* __restrict__ partials, int n) {
    int i = blockIdx.x * blockDim.x + threadIdx.x;
    if (i < n) row_ptr[i] += partials[i / SCAN_CHUNK];
}

// writes packed edge records: {src_idx, bitcast(norm)} per edge, CSR-ordered by dst
__global__ void fill_kernel(const int* __restrict__ src, const int* __restrict__ dst, int E,
                            const int* __restrict__ row_ptr, int* __restrict__ fill,
                            const float* __restrict__ dinv,
                            int2* __restrict__ csr_rec) {
    int e = blockIdx.x * blockDim.x + threadIdx.x;
    if (e < E) {
        int s = src[e], d = dst[e];
        int pos = atomicAdd(&fill[d], 1);
        int idx = row_ptr[d] + pos;
        float nm = dinv[s] * dinv[d];
        csr_rec[idx] = make_int2(s, __float_as_int(nm));
    }
}

__global__ void center_kernel(const int* __restrict__ batch, int n, int* __restrict__ center) {
    int i = blockIdx.x * blockDim.x + threadIdx.x;
    if (i < n) atomicMin(&center[batch[i]], i);
}

// ---------------- fp32 GEMM: Y[n,128] = X[n,128] @ W[128,128] ----------------
// BM=64 rows, BN=64 cols (blockIdx.y picks col half). LDS 66.5 KB -> 2 blocks/CU.
// GATHER: X row r comes from emb_table + z[r]*128 (fuses embedding lookup).
// __launch_bounds__(256,2) caps VGPRs at 128; #pragma unroll 2 keeps live set small.

template<bool GATHER>
__global__ __launch_bounds__(256, 2) void gemm_kernel(const float* __restrict__ X,
                                                      const int* __restrict__ z,
                                                      const float* __restrict__ Wm,
                                                      float* __restrict__ Y, int n) {
    __shared__ float Xs[64 * XS_LD];   // 33.8 KB
    __shared__ float Ws[H * 64];       // 32 KB
    int tid = threadIdx.x;
    int m0 = blockIdx.x * 64;
    int c0 = blockIdx.y * 64;

    // stage W cols [c0,c0+64): 128x64 floats = 2048 float4, 8 iters
    #pragma unroll
    for (int it = 0; it < 8; ++it) {
        int f  = it * 256 + tid;
        int r  = f >> 4;      // 16 float4 per row
        int c4 = f & 15;
        float4 v = *reinterpret_cast<const float4*>(Wm + r * H + c0 + c4 * 4);
        *reinterpret_cast<float4*>(Ws + r * 64 + c4 * 4) = v;
    }
    // stage X rows [m0,m0+64): 64x128 floats = 2048 float4, 8 iters
    #pragma unroll
    for (int it = 0; it < 8; ++it) {
        int f  = it * 256 + tid;
        int r  = f >> 5;      // 32 float4 per row
        int c4 = f & 31;
        int row = m0 + r;
        float4 v = make_float4(0.f, 0.f, 0.f, 0.f);
        if (row < n) {
            const float* sp = GATHER ? (X + (size_t)z[row] * H) : (X + (size_t)row * H);
            v = *reinterpret_cast<const float4*>(sp + c4 * 4);
        }
        *reinterpret_cast<float4*>(Xs + r * XS_LD + c4 * 4) = v;
    }
    __syncthreads();

    int tc = tid & 15;   // 16 col groups x 4 cols
    int tr = tid >> 4;   // 16 row groups x 4 rows
    int cc = tc * 4;
    int rr = tr * 4;
    float acc[4][4] = {};

    #pragma unroll 2
    for (int k = 0; k < H; k += 4) {
        float4 xv[4], wv[4];
        #pragma unroll
        for (int r = 0; r < 4; ++r)
            xv[r] = *reinterpret_cast<const float4*>(Xs + (rr + r) * XS_LD + k);
        #pragma unroll
        for (int kk = 0; kk < 4; ++kk)
            wv[kk] = *reinterpret_cast<const float4*>(Ws + (k + kk) * 64 + cc);
        #pragma unroll
        for (int kk = 0; kk < 4; ++kk) {
            float4 w = wv[kk];
            #pragma unroll
            for (int r = 0; r < 4; ++r) {
                float xs = (kk == 0) ? xv[r].x : (kk == 1) ? xv[r].y : (kk == 2) ? xv[r].z : xv[r].w;
                acc[r][0] = fmaf(xs, w.x, acc[r][0]);
                acc[r][1] = fmaf(xs, w.y, acc[r][1]);
                acc[r][2] = fmaf(xs, w.z, acc[r][2]);
                acc[r][3] = fmaf(xs, w.w, acc[r][3]);
            }
        }
    }

    #pragma unroll
    for (int r = 0; r < 4; ++r) {
        int row = m0 + rr + r;
        if (row < n) {
            float4 v = make_float4(acc[r][0], acc[r][1], acc[r][2], acc[r][3]);
            *reinterpret_cast<float4*>(Y + (size_t)row * H + c0 + cc) = v;
        }
    }
}

// ---------------- aggregation: Out[i] = b + sum_in h[src]*norm + h[i]*dinv^2 ----------------
// One 64-lane wave per node: lanes 0-31 take even edges, 32-63 odd edges
// (each half covers all 128 features as 32 float4). Unroll x2 -> 4 gathers
// in flight per wave. Halves combined with shfl_xor(32) at the end.

template<bool RELU>
__global__ __launch_bounds__(256) void agg_kernel(const float* __restrict__ Hbuf,
                                                  const int* __restrict__ row_ptr,
                                                  const int2* __restrict__ csr_rec,
                                                  const float* __restrict__ dinv,
                                                  const float* __restrict__ bias,
                                                  float* __restrict__ Out, int n) {
    int node = blockIdx.x * 4 + (threadIdx.x >> 6);
    if (node >= n) return;
    int lane = threadIdx.x & 63;
    int half = lane >> 5;       // 0: even edges, 1: odd edges
    int l32  = lane & 31;
    const float4* Hb = reinterpret_cast<const float4*>(Hbuf);

    float4 acc0 = make_float4(0.f, 0.f, 0.f, 0.f);
    float4 acc1 = make_float4(0.f, 0.f, 0.f, 0.f);
    if (half == 0) {  // self term + bias, added once
        float di = dinv[node];
        float s = di * di;
        float4 x  = Hb[(size_t)node * 32 + l32];
        float4 bv = reinterpret_cast<const float4*>(bias)[l32];
        acc0 = make_float4(bv.x + x.x * s, bv.y + x.y * s,
                           bv.z + x.z * s, bv.w + x.w * s);
    }

    int beg = row_ptr[node], end = row_ptr[node + 1];
    int j = beg + half;
    for (; j + 2 < end; j += 4) {   // two edges per half-wave in flight
        int2 r0 = csr_rec[j];
        int2 r1 = csr_rec[j + 2];
        float n0 = __int_as_float(r0.y);
        float n1 = __int_as_float(r1.y);
        float4 h0 = Hb[(size_t)r0.x * 32 + l32];
        float4 h1 = Hb[(size_t)r1.x * 32 + l32];
        acc0.x = fmaf(h0.x, n0, acc0.x); acc0.y = fmaf(h0.y, n0, acc0.y);
        acc0.z = fmaf(h0.z, n0, acc0.z); acc0.w = fmaf(h0.w, n0, acc0.w);
        acc1.x = fmaf(h1.x, n1, acc1.x); acc1.y = fmaf(h1.y, n1, acc1.y);
        acc1.z = fmaf(h1.z, n1, acc1.z); acc1.w = fmaf(h1.w, n1, acc1.w);
    }
    for (; j < end; j += 2) {
        int2 r0 = csr_rec[j];
        float n0 = __int_as_float(r0.y);
        float4 h0 = Hb[(size_t)r0.x * 32 + l32];
        acc0.x = fmaf(h0.x, n0, acc0.x); acc0.y = fmaf(h0.y, n0, acc0.y);
        acc0.z = fmaf(h0.z, n0, acc0.z); acc0.w = fmaf(h0.w, n0, acc0.w);
    }
    acc0.x += acc1.x; acc0.y += acc1.y; acc0.z += acc1.z; acc0.w += acc1.w;

    // combine the two halves (lane i gets lane i^32's partial)
    acc0.x += __shfl_xor(acc0.x, 32);
    acc0.y += __shfl_xor(acc0.y, 32);
    acc0.z += __shfl_xor(acc0.z, 32);
    acc0.w += __shfl_xor(acc0.w, 32);

    if (half == 0) {
        if (RELU) {
            acc0.x = fmaxf(acc0.x, 0.f); acc0.y = fmaxf(acc0.y, 0.f);
            acc0.z = fmaxf(acc0.z, 0.f); acc0.w = fmaxf(acc0.w, 0.f);
        }
        reinterpret_cast<float4*>(Out)[(size_t)node * 32 + l32] = acc0;
    }
}

// ---------------- readout: g = x[c]*x[c+1]; relu(g@W1+b1)@W2+b2 ----------------

__global__ __launch_bounds__(128) void readout_kernel(const float* __restrict__ X,
                                                      const int* __restrict__ center,
                                                      const float* __restrict__ w1,
                                                      const float* __restrict__ b1,
                                                      const float* __restrict__ w2,
                                                      const float* __restrict__ b2,
                                                      float* __restrict__ out, int n) {
    __shared__ float gv[H];
    __shared__ float red[H];
    int g = blockIdx.x;
    int c = threadIdx.x;
    int i0 = center[g];
    if (i0 > n - 1) i0 = n - 1;
    int i1 = (i0 + 1 < n) ? i0 + 1 : n - 1;
    gv[c] = X[(size_t)i0 * H + c] * X[(size_t)i1 * H + c];
    __syncthreads();
    float acc = b1[c];
    #pragma unroll 8
    for (int k = 0; k < H; ++k)
        acc = fmaf(gv[k], w1[k * H + c], acc);
    acc = fmaxf(acc, 0.f);
    red[c] = acc * w2[c];
    __syncthreads();
    for (int off = 64; off > 0; off >>= 1) {
        if (c < off) red[c] += red[c + off];
        __syncthreads();
    }
    if (c == 0) out[g] = red[0] + b2[0];
}

// ---------------- launcher ----------------

static inline size_t align_up(size_t x) { return (x + 255) & ~(size_t)255; }

extern "C" void kernel_launch(void* const* d_in, const int* in_sizes, int n_in,
                              void* d_out, int out_size, void* d_ws, size_t ws_size,
                              hipStream_t stream) {
    const int n = in_sizes[0];
    const int E = in_sizes[1] / 2;
    const int G = out_size;  // output is [G,1]

    const int*   z      = (const int*)d_in[0];
    const int*   ei     = (const int*)d_in[1];
    const int*   batch  = (const int*)d_in[2];
    const float* emb    = (const float*)d_in[4];
    const float* w0     = (const float*)d_in[5];
    const float* b0     = (const float*)d_in[6];
    const float* w1     = (const float*)d_in[7];
    const float* b1     = (const float*)d_in[8];
    const float* w2     = (const float*)d_in[9];
    const float* b2     = (const float*)d_in[10];
    const float* lin1_w = (const float*)d_in[11];
    const float* lin1_b = (const float*)d_in[12];
    const float* lin2_w = (const float*)d_in[13];
    const float* lin2_b = (const float*)d_in[14];

    const int* e_src = ei;
    const int* e_dst = ei + E;

    const int nPart = (n + SCAN_CHUNK - 1) / SCAN_CHUNK;  // 25 for n=50000 (<=64 required)

    char* p = (char*)d_ws;
    int*   cnt      = (int*)p;  p += align_up((size_t)n * 4);
    int*   row_ptr  = (int*)p;  p += align_up((size_t)(n + 1) * 4);
    int*   fill     = (int*)p;  p += align_up((size_t)n * 4);
    int*   center   = (int*)p;  p += align_up((size_t)G * 4);
    int*   partials = (int*)p;  p += align_up((size_t)64 * 4);
    int2*  csr_rec  = (int2*)p; p += align_up((size_t)E * 8);
    float* dinv     = (float*)p; p += align_up((size_t)n * 4);
    float* bufA     = (float*)p; p += align_up((size_t)n * H * 4);
    float* bufB     = (float*)p; p += align_up((size_t)n * H * 4);

    const int TB = 256;
    dim3 gN((n + TB - 1) / TB);
    dim3 gE((E + TB - 1) / TB);
    dim3 gG((G + TB - 1) / TB);

    // build degree / dinv / CSR
    set_int_kernel<<<gN, TB, 0, stream>>>(cnt, n, 0);
    set_int_kernel<<<gN, TB, 0, stream>>>(fill, n, 0);
    set_int_kernel<<<gG, TB, 0, stream>>>(center, G, 0x7fffffff);
    count_kernel<<<gE, TB, 0, stream>>>(e_dst, E, cnt);
    scan_local<<<nPart, 256, 0, stream>>>(cnt, row_ptr, partials, dinv, n);
    scan_partials<<<1, 64, 0, stream>>>(partials, row_ptr, nPart, n);
    scan_add<<<gN, TB, 0, stream>>>(row_ptr, partials, n);
    fill_kernel<<<gE, TB, 0, stream>>>(e_src, e_dst, E, row_ptr, fill, dinv, csr_rec);
    center_kernel<<<gN, TB, 0, stream>>>(batch, n, center);

    dim3 gemm_grid((n + 63) / 64, 2);
    dim3 agg_grid((n + 3) / 4);

    // layer 0 (embedding gather fused into GEMM staging)
    gemm_kernel<true><<<gemm_grid, 256, 0, stream>>>(emb, z, w0, bufB, n);
    agg_kernel<true><<<agg_grid, 256, 0, stream>>>(bufB, row_ptr, csr_rec, dinv, b0, bufA, n);
    // layer 1
    gemm_kernel<false><<<gemm_grid, 256, 0, stream>>>(bufA, nullptr, w1, bufB, n);
    agg_kernel<true><<<agg_grid, 256, 0, stream>>>(bufB, row_ptr, csr_rec, dinv, b1, bufA, n);
    // layer 2 (no relu)
    gemm_kernel<false><<<gemm_grid, 256, 0, stream>>>(bufA, nullptr, w2, bufB, n);
    agg_kernel<false><<<agg_grid, 256, 0, stream>>>(bufB, row_ptr, csr_rec, dinv, b2, bufA, n);

    // readout
    readout_kernel<<<G, 128, 0, stream>>>(bufA, center, lin1_w, lin1_b, lin2_w, lin2_b,
                                          (float*)d_out, n);
}

// Round 9
// 396.348 us; speedup vs baseline: 5.8279x; 1.0050x over previous
//
#include <hip/hip_runtime.h>
#include <cstdint>
#include <cstddef>

#define H 128
#define XS_LD 132   // padded LDS stride for X tile (breaks 512B bank aliasing)
#define SCAN_CHUNK 2048   // elements per scan_local block (256 thr x 8)

// ---------------- utility kernels ----------------

__global__ void set_int_kernel(int* __restrict__ p, int n, int val) {
    int i = blockIdx.x * blockDim.x + threadIdx.x;
    if (i < n) p[i] = val;
}

__global__ void count_kernel(const int* __restrict__ dst, int E, int* __restrict__ cnt) {
    int e = blockIdx.x * blockDim.x + threadIdx.x;
    if (e < E) atomicAdd(&cnt[dst[e]], 1);
}

// per-block exclusive scan of cnt into row_ptr; block totals -> partials.
// Also computes dinv[i] = rsqrt(cnt[i]+1) (self-loop degree) for free.
__global__ __launch_bounds__(256) void scan_local(const int* __restrict__ cnt,
                                                  int* __restrict__ row_ptr,
                                                  int* __restrict__ partials,
                                                  float* __restrict__ dinv, int n) {
    __shared__ int sm[256];
    int tid = threadIdx.x;
    int base = blockIdx.x * SCAN_CHUNK + tid * 8;
    int v[8];
    int s = 0;
    #pragma unroll
    for (int j = 0; j < 8; ++j) {
        int i = base + j;
        v[j] = (i < n) ? cnt[i] : 0;
        if (i < n) dinv[i] = rsqrtf((float)(v[j] + 1));
        s += v[j];
    }
    sm[tid] = s;
    __syncthreads();
    #pragma unroll
    for (int off = 1; off < 256; off <<= 1) {
        int t = (tid >= off) ? sm[tid - off] : 0;
        __syncthreads();
        sm[tid] += t;
        __syncthreads();
    }
    int excl = sm[tid] - s;   // exclusive prefix within block
    if (tid == 255) partials[blockIdx.x] = sm[255];
    #pragma unroll
    for (int j = 0; j < 8; ++j) {
        int i = base + j;
        if (i < n) row_ptr[i] = excl;
        excl += v[j];
    }
}

// single-wave scan of block partials (nPart <= 64); writes row_ptr[n] = total.
__global__ __launch_bounds__(64) void scan_partials(int* __restrict__ partials,
                                                    int* __restrict__ row_ptr,
                                                    int nPart, int n) {
    int tid = threadIdx.x;
    int v = (tid < nPart) ? partials[tid] : 0;
    int ps = v;
    #pragma unroll
    for (int off = 1; off < 64; off <<= 1) {
        int t = __shfl_up(ps, off);
        if (tid >= off) ps += t;
    }
    if (tid < nPart) partials[tid] = ps - v;  // exclusive
    if (tid == 63) row_ptr[n] = ps;           // total edge count
}

__global__ void scan_add(int* __restrict__ row_ptr, const int* __restrict__ partials, int n) {
    int i = blockIdx.x * blockDim.x + threadIdx.x;
    if (i < n) row_ptr[i] += partials[i / SCAN_CHUNK];
}

// writes packed edge records: {src_idx, bitcast(norm)} per edge, CSR-ordered by dst
__global__ void fill_kernel(const int* __restrict__ src, const int* __restrict__ dst, int E,
                            const int* __restrict__ row_ptr, int* __restrict__ fill,
                            const float* __restrict__ dinv,
                            int2* __restrict__ csr_rec) {
    int e = blockIdx.x * blockDim.x + threadIdx.x;
    if (e < E) {
        int s = src[e], d = dst[e];
        int pos = atomicAdd(&fill[d], 1);
        int idx = row_ptr[d] + pos;
        float nm = dinv[s] * dinv[d];
        csr_rec[idx] = make_int2(s, __float_as_int(nm));
    }
}

__global__ void center_kernel(const int* __restrict__ batch, int n, int* __restrict__ center) {
    int i = blockIdx.x * blockDim.x + threadIdx.x;
    if (i < n) atomicMin(&center[batch[i]], i);
}

// ---------------- fp32 GEMM: Y[n,128] = X[n,128] @ W[128,128] ----------------
// BM=64 rows, BN=64 cols (blockIdx.y picks col half). LDS 66.5 KB -> 2 blocks/CU.
// GATHER: X row r comes from emb_table + z[r]*128 (fuses embedding lookup).
// __launch_bounds__(256,2) caps VGPRs at 128; #pragma unroll 2 keeps live set small.

template<bool GATHER>
__global__ __launch_bounds__(256, 2) void gemm_kernel(const float* __restrict__ X,
                                                      const int* __restrict__ z,
                                                      const float* __restrict__ Wm,
                                                      float* __restrict__ Y, int n) {
    __shared__ float Xs[64 * XS_LD];   // 33.8 KB
    __shared__ float Ws[H * 64];       // 32 KB
    int tid = threadIdx.x;
    int m0 = blockIdx.x * 64;
    int c0 = blockIdx.y * 64;

    // stage W cols [c0,c0+64): 128x64 floats = 2048 float4, 8 iters
    #pragma unroll
    for (int it = 0; it < 8; ++it) {
        int f  = it * 256 + tid;
        int r  = f >> 4;      // 16 float4 per row
        int c4 = f & 15;
        float4 v = *reinterpret_cast<const float4*>(Wm + r * H + c0 + c4 * 4);
        *reinterpret_cast<float4*>(Ws + r * 64 + c4 * 4) = v;
    }
    // stage X rows [m0,m0+64): 64x128 floats = 2048 float4, 8 iters
    #pragma unroll
    for (int it = 0; it < 8; ++it) {
        int f  = it * 256 + tid;
        int r  = f >> 5;      // 32 float4 per row
        int c4 = f & 31;
        int row = m0 + r;
        float4 v = make_float4(0.f, 0.f, 0.f, 0.f);
        if (row < n) {
            const float* sp = GATHER ? (X + (size_t)z[row] * H) : (X + (size_t)row * H);
            v = *reinterpret_cast<const float4*>(sp + c4 * 4);
        }
        *reinterpret_cast<float4*>(Xs + r * XS_LD + c4 * 4) = v;
    }
    __syncthreads();

    int tc = tid & 15;   // 16 col groups x 4 cols
    int tr = tid >> 4;   // 16 row groups x 4 rows
    int cc = tc * 4;
    int rr = tr * 4;
    float acc[4][4] = {};

    #pragma unroll 2
    for (int k = 0; k < H; k += 4) {
        float4 xv[4], wv[4];
        #pragma unroll
        for (int r = 0; r < 4; ++r)
            xv[r] = *reinterpret_cast<const float4*>(Xs + (rr + r) * XS_LD + k);
        #pragma unroll
        for (int kk = 0; kk < 4; ++kk)
            wv[kk] = *reinterpret_cast<const float4*>(Ws + (k + kk) * 64 + cc);
        #pragma unroll
        for (int kk = 0; kk < 4; ++kk) {
            float4 w = wv[kk];
            #pragma unroll
            for (int r = 0; r < 4; ++r) {
                float xs = (kk == 0) ? xv[r].x : (kk == 1) ? xv[r].y : (kk == 2) ? xv[r].z : xv[r].w;
                acc[r][0] = fmaf(xs, w.x, acc[r][0]);
                acc[r][1] = fmaf(xs, w.y, acc[r][1]);
                acc[r][2] = fmaf(xs, w.z, acc[r][2]);
                acc[r][3] = fmaf(xs, w.w, acc[r][3]);
            }
        }
    }

    #pragma unroll
    for (int r = 0; r < 4; ++r) {
        int row = m0 + rr + r;
        if (row < n) {
            float4 v = make_float4(acc[r][0], acc[r][1], acc[r][2], acc[r][3]);
            *reinterpret_cast<float4*>(Y + (size_t)row * H + c0 + cc) = v;
        }
    }
}

// ---------------- aggregation: Out[i] = b + sum_in h[src]*norm + h[i]*dinv^2 ----------------
// One 64-lane wave per node: lanes 0-31 take even edges, 32-63 odd edges.
// 4-stream unroll per half-wave -> 8 independent 512B gathers in flight per wave.

template<bool RELU>
__global__ __launch_bounds__(256) void agg_kernel(const float* __restrict__ Hbuf,
                                                  const int* __restrict__ row_ptr,
                                                  const int2* __restrict__ csr_rec,
                                                  const float* __restrict__ dinv,
                                                  const float* __restrict__ bias,
                                                  float* __restrict__ Out, int n) {
    int node = blockIdx.x * 4 + (threadIdx.x >> 6);
    if (node >= n) return;
    int lane = threadIdx.x & 63;
    int half = lane >> 5;       // 0: even edges, 1: odd edges
    int l32  = lane & 31;
    const float4* Hb = reinterpret_cast<const float4*>(Hbuf);

    float4 acc0 = make_float4(0.f, 0.f, 0.f, 0.f);
    float4 acc1 = make_float4(0.f, 0.f, 0.f, 0.f);
    float4 acc2 = make_float4(0.f, 0.f, 0.f, 0.f);
    float4 acc3 = make_float4(0.f, 0.f, 0.f, 0.f);
    if (half == 0) {  // self term + bias, added once
        float di = dinv[node];
        float s = di * di;
        float4 x  = Hb[(size_t)node * 32 + l32];
        float4 bv = reinterpret_cast<const float4*>(bias)[l32];
        acc0 = make_float4(bv.x + x.x * s, bv.y + x.y * s,
                           bv.z + x.z * s, bv.w + x.w * s);
    }

    int beg = row_ptr[node], end = row_ptr[node + 1];
    int j = beg + half;
    // 4-stream main loop: edges j, j+2, j+4, j+6 gathered concurrently
    for (; j + 6 < end; j += 8) {
        int2 r0 = csr_rec[j];
        int2 r1 = csr_rec[j + 2];
        int2 r2 = csr_rec[j + 4];
        int2 r3 = csr_rec[j + 6];
        float4 h0 = Hb[(size_t)r0.x * 32 + l32];
        float4 h1 = Hb[(size_t)r1.x * 32 + l32];
        float4 h2 = Hb[(size_t)r2.x * 32 + l32];
        float4 h3 = Hb[(size_t)r3.x * 32 + l32];
        float n0 = __int_as_float(r0.y);
        float n1 = __int_as_float(r1.y);
        float n2 = __int_as_float(r2.y);
        float n3 = __int_as_float(r3.y);
        acc0.x = fmaf(h0.x, n0, acc0.x); acc0.y = fmaf(h0.y, n0, acc0.y);
        acc0.z = fmaf(h0.z, n0, acc0.z); acc0.w = fmaf(h0.w, n0, acc0.w);
        acc1.x = fmaf(h1.x, n1, acc1.x); acc1.y = fmaf(h1.y, n1, acc1.y);
        acc1.z = fmaf(h1.z, n1, acc1.z); acc1.w = fmaf(h1.w, n1, acc1.w);
        acc2.x = fmaf(h2.x, n2, acc2.x); acc2.y = fmaf(h2.y, n2, acc2.y);
        acc2.z = fmaf(h2.z, n2, acc2.z); acc2.w = fmaf(h2.w, n2, acc2.w);
        acc3.x = fmaf(h3.x, n3, acc3.x); acc3.y = fmaf(h3.y, n3, acc3.y);
        acc3.z = fmaf(h3.z, n3, acc3.z); acc3.w = fmaf(h3.w, n3, acc3.w);
    }
    // tail
    for (; j < end; j += 2) {
        int2 r0 = csr_rec[j];
        float n0 = __int_as_float(r0.y);
        float4 h0 = Hb[(size_t)r0.x * 32 + l32];
        acc0.x = fmaf(h0.x, n0, acc0.x); acc0.y = fmaf(h0.y, n0, acc0.y);
        acc0.z = fmaf(h0.z, n0, acc0.z); acc0.w = fmaf(h0.w, n0, acc0.w);
    }
    acc0.x += acc1.x + acc2.x + acc3.x;
    acc0.y += acc1.y + acc2.y + acc3.y;
    acc0.z += acc1.z + acc2.z + acc3.z;
    acc0.w += acc1.w + acc2.w + acc3.w;

    // combine the two halves (lane i gets lane i^32's partial)
    acc0.x += __shfl_xor(acc0.x, 32);
    acc0.y += __shfl_xor(acc0.y, 32);
    acc0.z += __shfl_xor(acc0.z, 32);
    acc0.w += __shfl_xor(acc0.w, 32);

    if (half == 0) {
        if (RELU) {
            acc0.x = fmaxf(acc0.x, 0.f); acc0.y = fmaxf(acc0.y, 0.f);
            acc0.z = fmaxf(acc0.z, 0.f); acc0.w = fmaxf(acc0.w, 0.f);
        }
        reinterpret_cast<float4*>(Out)[(size_t)node * 32 + l32] = acc0;
    }
}

// ---------------- readout: g = x[c]*x[c+1]; relu(g@W1+b1)@W2+b2 ----------------

__global__ __launch_bounds__(128) void readout_kernel(const float* __restrict__ X,
                                                      const int* __restrict__ center,
                                                      const float* __restrict__ w1,
                                                      const float* __restrict__ b1,
                                                      const float* __restrict__ w2,
                                                      const float* __restrict__ b2,
                                                      float* __restrict__ out, int n) {
    __shared__ float gv[H];
    __shared__ float red[H];
    int g = blockIdx.x;
    int c = threadIdx.x;
    int i0 = center[g];
    if (i0 > n - 1) i0 = n - 1;
    int i1 = (i0 + 1 < n) ? i0 + 1 : n - 1;
    gv[c] = X[(size_t)i0 * H + c] * X[(size_t)i1 * H + c];
    __syncthreads();
    float acc = b1[c];
    #pragma unroll 8
    for (int k = 0; k < H; ++k)
        acc = fmaf(gv[k], w1[k * H + c], acc);
    acc = fmaxf(acc, 0.f);
    red[c] = acc * w2[c];
    __syncthreads();
    for (int off = 64; off > 0; off >>= 1) {
        if (c < off) red[c] += red[c + off];
        __syncthreads();
    }
    if (c == 0) out[g] = red[0] + b2[0];
}

// ---------------- launcher ----------------

static inline size_t align_up(size_t x) { return (x + 255) & ~(size_t)255; }

extern "C" void kernel_launch(void* const* d_in, const int* in_sizes, int n_in,
                              void* d_out, int out_size, void* d_ws, size_t ws_size,
                              hipStream_t stream) {
    const int n = in_sizes[0];
    const int E = in_sizes[1] / 2;
    const int G = out_size;  // output is [G,1]

    const int*   z      = (const int*)d_in[0];
    const int*   ei     = (const int*)d_in[1];
    const int*   batch  = (const int*)d_in[2];
    const float* emb    = (const float*)d_in[4];
    const float* w0     = (const float*)d_in[5];
    const float* b0     = (const float*)d_in[6];
    const float* w1     = (const float*)d_in[7];
    const float* b1     = (const float*)d_in[8];
    const float* w2     = (const float*)d_in[9];
    const float* b2     = (const float*)d_in[10];
    const float* lin1_w = (const float*)d_in[11];
    const float* lin1_b = (const float*)d_in[12];
    const float* lin2_w = (const float*)d_in[13];
    const float* lin2_b = (const float*)d_in[14];

    const int* e_src = ei;
    const int* e_dst = ei + E;

    const int nPart = (n + SCAN_CHUNK - 1) / SCAN_CHUNK;  // 25 for n=50000 (<=64 required)

    char* p = (char*)d_ws;
    int*   cnt      = (int*)p;  p += align_up((size_t)n * 4);
    int*   row_ptr  = (int*)p;  p += align_up((size_t)(n + 1) * 4);
    int*   fill     = (int*)p;  p += align_up((size_t)n * 4);
    int*   center   = (int*)p;  p += align_up((size_t)G * 4);
    int*   partials = (int*)p;  p += align_up((size_t)64 * 4);
    int2*  csr_rec  = (int2*)p; p += align_up((size_t)E * 8);
    float* dinv     = (float*)p; p += align_up((size_t)n * 4);
    float* bufA     = (float*)p; p += align_up((size_t)n * H * 4);
    float* bufB     = (float*)p; p += align_up((size_t)n * H * 4);

    const int TB = 256;
    dim3 gN((n + TB - 1) / TB);
    dim3 gE((E + TB - 1) / TB);
    dim3 gG((G + TB - 1) / TB);

    // build degree / dinv / CSR
    set_int_kernel<<<gN, TB, 0, stream>>>(cnt, n, 0);
    set_int_kernel<<<gN, TB, 0, stream>>>(fill, n, 0);
    set_int_kernel<<<gG, TB, 0, stream>>>(center, G, 0x7fffffff);
    count_kernel<<<gE, TB, 0, stream>>>(e_dst, E, cnt);
    scan_local<<<nPart, 256, 0, stream>>>(cnt, row_ptr, partials, dinv, n);
    scan_partials<<<1, 64, 0, stream>>>(partials, row_ptr, nPart, n);
    scan_add<<<gN, TB, 0, stream>>>(row_ptr, partials, n);
    fill_kernel<<<gE, TB, 0, stream>>>(e_src, e_dst, E, row_ptr, fill, dinv, csr_rec);
    center_kernel<<<gN, TB, 0, stream>>>(batch, n, center);

    dim3 gemm_grid((n + 63) / 64, 2);
    dim3 agg_grid((n + 3) / 4);

    // layer 0 (embedding gather fused into GEMM staging)
    gemm_kernel<true><<<gemm_grid, 256, 0, stream>>>(emb, z, w0, bufB, n);
    agg_kernel<true><<<agg_grid, 256, 0, stream>>>(bufB, row_ptr, csr_rec, dinv, b0, bufA, n);
    // layer 1
    gemm_kernel<false><<<gemm_grid, 256, 0, stream>>>(bufA, nullptr, w1, bufB, n);
    agg_kernel<true><<<agg_grid, 256, 0, stream>>>(bufB, row_ptr, csr_rec, dinv, b1, bufA, n);
    // layer 2 (no relu)
    gemm_kernel<false><<<gemm_grid, 256, 0, stream>>>(bufA, nullptr, w2, bufB, n);
    agg_kernel<false><<<agg_grid, 256, 0, stream>>>(bufB, row_ptr, csr_rec, dinv, b2, bufA, n);

    // readout
    readout_kernel<<<G, 128, 0, stream>>>(bufA, center, lin1_w, lin1_b, lin2_w, lin2_b,
                                          (float*)d_out, n);
}

// Round 10
// 339.873 us; speedup vs baseline: 6.7964x; 1.1662x over previous
//
#include <hip/hip_runtime.h>
#include <cstdint>
#include <cstddef>

#define H 128
#define XS_LD 132   // padded LDS stride for X tile (breaks 512B bank aliasing)
#define SCAN_CHUNK 2048   // elements per scan_local block (256 thr x 8)

// pack two fp32 -> one uint holding 2x bf16 (RNE). lo -> low half, hi -> high half.
__device__ inline unsigned pack_bf2(float lo, float hi) {
    unsigned ulo = __float_as_uint(lo);
    unsigned uhi = __float_as_uint(hi);
    ulo += 0x7FFFu + ((ulo >> 16) & 1u);
    uhi += 0x7FFFu + ((uhi >> 16) & 1u);
    return (ulo >> 16) | (uhi & 0xFFFF0000u);
}

// ---------------- utility kernels ----------------

__global__ void set_int_kernel(int* __restrict__ p, int n, int val) {
    int i = blockIdx.x * blockDim.x + threadIdx.x;
    if (i < n) p[i] = val;
}

__global__ void count_kernel(const int* __restrict__ dst, int E, int* __restrict__ cnt) {
    int e = blockIdx.x * blockDim.x + threadIdx.x;
    if (e < E) atomicAdd(&cnt[dst[e]], 1);
}

// per-block exclusive scan of cnt into row_ptr; block totals -> partials.
// Also computes dinv[i] = rsqrt(cnt[i]+1) (self-loop degree) for free.
__global__ __launch_bounds__(256) void scan_local(const int* __restrict__ cnt,
                                                  int* __restrict__ row_ptr,
                                                  int* __restrict__ partials,
                                                  float* __restrict__ dinv, int n) {
    __shared__ int sm[256];
    int tid = threadIdx.x;
    int base = blockIdx.x * SCAN_CHUNK + tid * 8;
    int v[8];
    int s = 0;
    #pragma unroll
    for (int j = 0; j < 8; ++j) {
        int i = base + j;
        v[j] = (i < n) ? cnt[i] : 0;
        if (i < n) dinv[i] = rsqrtf((float)(v[j] + 1));
        s += v[j];
    }
    sm[tid] = s;
    __syncthreads();
    #pragma unroll
    for (int off = 1; off < 256; off <<= 1) {
        int t = (tid >= off) ? sm[tid - off] : 0;
        __syncthreads();
        sm[tid] += t;
        __syncthreads();
    }
    int excl = sm[tid] - s;   // exclusive prefix within block
    if (tid == 255) partials[blockIdx.x] = sm[255];
    #pragma unroll
    for (int j = 0; j < 8; ++j) {
        int i = base + j;
        if (i < n) row_ptr[i] = excl;
        excl += v[j];
    }
}

// single-wave scan of block partials (nPart <= 64); writes row_ptr[n] = total.
__global__ __launch_bounds__(64) void scan_partials(int* __restrict__ partials,
                                                    int* __restrict__ row_ptr,
                                                    int nPart, int n) {
    int tid = threadIdx.x;
    int v = (tid < nPart) ? partials[tid] : 0;
    int ps = v;
    #pragma unroll
    for (int off = 1; off < 64; off <<= 1) {
        int t = __shfl_up(ps, off);
        if (tid >= off) ps += t;
    }
    if (tid < nPart) partials[tid] = ps - v;  // exclusive
    if (tid == 63) row_ptr[n] = ps;           // total edge count
}

__global__ void scan_add(int* __restrict__ row_ptr, const int* __restrict__ partials, int n) {
    int i = blockIdx.x * blockDim.x + threadIdx.x;
    if (i < n) row_ptr[i] += partials[i / SCAN_CHUNK];
}

// writes packed edge records: {src_idx, bitcast(norm)} per edge, CSR-ordered by dst
__global__ void fill_kernel(const int* __restrict__ src, const int* __restrict__ dst, int E,
                            const int* __restrict__ row_ptr, int* __restrict__ fill,
                            const float* __restrict__ dinv,
                            int2* __restrict__ csr_rec) {
    int e = blockIdx.x * blockDim.x + threadIdx.x;
    if (e < E) {
        int s = src[e], d = dst[e];
        int pos = atomicAdd(&fill[d], 1);
        int idx = row_ptr[d] + pos;
        float nm = dinv[s] * dinv[d];
        csr_rec[idx] = make_int2(s, __float_as_int(nm));
    }
}

__global__ void center_kernel(const int* __restrict__ batch, int n, int* __restrict__ center) {
    int i = blockIdx.x * blockDim.x + threadIdx.x;
    if (i < n) atomicMin(&center[batch[i]], i);
}

// ---------------- fp32 GEMM: Yb[n,128](bf16) = X[n,128] @ W[128,128] ----------------
// BM=64 rows, BN=64 cols (blockIdx.y picks col half). LDS 66.5 KB -> 2 blocks/CU.
// GATHER: X row r comes from emb_table + z[r]*128 (fuses embedding lookup).
// Output written as packed bf16 (RNE) -- consumed only by agg's gather.

template<bool GATHER>
__global__ __launch_bounds__(256, 2) void gemm_kernel(const float* __restrict__ X,
                                                      const int* __restrict__ z,
                                                      const float* __restrict__ Wm,
                                                      unsigned* __restrict__ Yb, int n) {
    __shared__ float Xs[64 * XS_LD];   // 33.8 KB
    __shared__ float Ws[H * 64];       // 32 KB
    int tid = threadIdx.x;
    int m0 = blockIdx.x * 64;
    int c0 = blockIdx.y * 64;

    // stage W cols [c0,c0+64): 128x64 floats = 2048 float4, 8 iters
    #pragma unroll
    for (int it = 0; it < 8; ++it) {
        int f  = it * 256 + tid;
        int r  = f >> 4;      // 16 float4 per row
        int c4 = f & 15;
        float4 v = *reinterpret_cast<const float4*>(Wm + r * H + c0 + c4 * 4);
        *reinterpret_cast<float4*>(Ws + r * 64 + c4 * 4) = v;
    }
    // stage X rows [m0,m0+64): 64x128 floats = 2048 float4, 8 iters
    #pragma unroll
    for (int it = 0; it < 8; ++it) {
        int f  = it * 256 + tid;
        int r  = f >> 5;      // 32 float4 per row
        int c4 = f & 31;
        int row = m0 + r;
        float4 v = make_float4(0.f, 0.f, 0.f, 0.f);
        if (row < n) {
            const float* sp = GATHER ? (X + (size_t)z[row] * H) : (X + (size_t)row * H);
            v = *reinterpret_cast<const float4*>(sp + c4 * 4);
        }
        *reinterpret_cast<float4*>(Xs + r * XS_LD + c4 * 4) = v;
    }
    __syncthreads();

    int tc = tid & 15;   // 16 col groups x 4 cols
    int tr = tid >> 4;   // 16 row groups x 4 rows
    int cc = tc * 4;
    int rr = tr * 4;
    float acc[4][4] = {};

    #pragma unroll 2
    for (int k = 0; k < H; k += 4) {
        float4 xv[4], wv[4];
        #pragma unroll
        for (int r = 0; r < 4; ++r)
            xv[r] = *reinterpret_cast<const float4*>(Xs + (rr + r) * XS_LD + k);
        #pragma unroll
        for (int kk = 0; kk < 4; ++kk)
            wv[kk] = *reinterpret_cast<const float4*>(Ws + (k + kk) * 64 + cc);
        #pragma unroll
        for (int kk = 0; kk < 4; ++kk) {
            float4 w = wv[kk];
            #pragma unroll
            for (int r = 0; r < 4; ++r) {
                float xs = (kk == 0) ? xv[r].x : (kk == 1) ? xv[r].y : (kk == 2) ? xv[r].z : xv[r].w;
                acc[r][0] = fmaf(xs, w.x, acc[r][0]);
                acc[r][1] = fmaf(xs, w.y, acc[r][1]);
                acc[r][2] = fmaf(xs, w.z, acc[r][2]);
                acc[r][3] = fmaf(xs, w.w, acc[r][3]);
            }
        }
    }

    // epilogue: pack 4 cols -> uint2 (4x bf16), store 8B per row
    #pragma unroll
    for (int r = 0; r < 4; ++r) {
        int row = m0 + rr + r;
        if (row < n) {
            uint2 pv;
            pv.x = pack_bf2(acc[r][0], acc[r][1]);
            pv.y = pack_bf2(acc[r][2], acc[r][3]);
            *reinterpret_cast<uint2*>(Yb + (size_t)row * 64 + (c0 + cc) / 2) = pv;
        }
    }
}

// ---------------- aggregation: Out[i] = b + sum_in h[src]*norm + h[i]*dinv^2 ----------------
// h is bf16-packed [n][128] (64 uints/row). One 64-lane wave per node:
// lanes 0-31 even edges, 32-63 odd edges; lane covers cols [4*l32, 4*l32+4)
// as one uint2 (8B). 4-stream unroll -> 8 independent 256B gathers in flight.
// Accumulation in fp32; output written fp32.

template<bool RELU>
__global__ __launch_bounds__(256) void agg_kernel(const unsigned* __restrict__ Hb,
                                                  const int* __restrict__ row_ptr,
                                                  const int2* __restrict__ csr_rec,
                                                  const float* __restrict__ dinv,
                                                  const float* __restrict__ bias,
                                                  float* __restrict__ Out, int n) {
    int node = blockIdx.x * 4 + (threadIdx.x >> 6);
    if (node >= n) return;
    int lane = threadIdx.x & 63;
    int half = lane >> 5;       // 0: even edges, 1: odd edges
    int l32  = lane & 31;
    const uint2* Hu = reinterpret_cast<const uint2*>(Hb);

    float4 acc0 = make_float4(0.f, 0.f, 0.f, 0.f);
    float4 acc1 = make_float4(0.f, 0.f, 0.f, 0.f);
    float4 acc2 = make_float4(0.f, 0.f, 0.f, 0.f);
    float4 acc3 = make_float4(0.f, 0.f, 0.f, 0.f);
    if (half == 0) {  // self term + bias, added once
        float di = dinv[node];
        float s = di * di;
        uint2 u = Hu[(size_t)node * 32 + l32];
        float4 bv = reinterpret_cast<const float4*>(bias)[l32];
        acc0.x = bv.x + __uint_as_float(u.x << 16) * s;
        acc0.y = bv.y + __uint_as_float(u.x & 0xFFFF0000u) * s;
        acc0.z = bv.z + __uint_as_float(u.y << 16) * s;
        acc0.w = bv.w + __uint_as_float(u.y & 0xFFFF0000u) * s;
    }

    int beg = row_ptr[node], end = row_ptr[node + 1];
    int j = beg + half;
    // 4-stream main loop: edges j, j+2, j+4, j+6 gathered concurrently
    for (; j + 6 < end; j += 8) {
        int2 r0 = csr_rec[j];
        int2 r1 = csr_rec[j + 2];
        int2 r2 = csr_rec[j + 4];
        int2 r3 = csr_rec[j + 6];
        uint2 u0 = Hu[(size_t)r0.x * 32 + l32];
        uint2 u1 = Hu[(size_t)r1.x * 32 + l32];
        uint2 u2 = Hu[(size_t)r2.x * 32 + l32];
        uint2 u3 = Hu[(size_t)r3.x * 32 + l32];
        float n0 = __int_as_float(r0.y);
        float n1 = __int_as_float(r1.y);
        float n2 = __int_as_float(r2.y);
        float n3 = __int_as_float(r3.y);
        acc0.x = fmaf(__uint_as_float(u0.x << 16),        n0, acc0.x);
        acc0.y = fmaf(__uint_as_float(u0.x & 0xFFFF0000u), n0, acc0.y);
        acc0.z = fmaf(__uint_as_float(u0.y << 16),        n0, acc0.z);
        acc0.w = fmaf(__uint_as_float(u0.y & 0xFFFF0000u), n0, acc0.w);
        acc1.x = fmaf(__uint_as_float(u1.x << 16),        n1, acc1.x);
        acc1.y = fmaf(__uint_as_float(u1.x & 0xFFFF0000u), n1, acc1.y);
        acc1.z = fmaf(__uint_as_float(u1.y << 16),        n1, acc1.z);
        acc1.w = fmaf(__uint_as_float(u1.y & 0xFFFF0000u), n1, acc1.w);
        acc2.x = fmaf(__uint_as_float(u2.x << 16),        n2, acc2.x);
        acc2.y = fmaf(__uint_as_float(u2.x & 0xFFFF0000u), n2, acc2.y);
        acc2.z = fmaf(__uint_as_float(u2.y << 16),        n2, acc2.z);
        acc2.w = fmaf(__uint_as_float(u2.y & 0xFFFF0000u), n2, acc2.w);
        acc3.x = fmaf(__uint_as_float(u3.x << 16),        n3, acc3.x);
        acc3.y = fmaf(__uint_as_float(u3.x & 0xFFFF0000u), n3, acc3.y);
        acc3.z = fmaf(__uint_as_float(u3.y << 16),        n3, acc3.z);
        acc3.w = fmaf(__uint_as_float(u3.y & 0xFFFF0000u), n3, acc3.w);
    }
    // tail
    for (; j < end; j += 2) {
        int2 r0 = csr_rec[j];
        float n0 = __int_as_float(r0.y);
        uint2 u0 = Hu[(size_t)r0.x * 32 + l32];
        acc0.x = fmaf(__uint_as_float(u0.x << 16),        n0, acc0.x);
        acc0.y = fmaf(__uint_as_float(u0.x & 0xFFFF0000u), n0, acc0.y);
        acc0.z = fmaf(__uint_as_float(u0.y << 16),        n0, acc0.z);
        acc0.w = fmaf(__uint_as_float(u0.y & 0xFFFF0000u), n0, acc0.w);
    }
    acc0.x += acc1.x + acc2.x + acc3.x;
    acc0.y += acc1.y + acc2.y + acc3.y;
    acc0.z += acc1.z + acc2.z + acc3.z;
    acc0.w += acc1.w + acc2.w + acc3.w;

    // combine the two halves (lane i gets lane i^32's partial)
    acc0.x += __shfl_xor(acc0.x, 32);
    acc0.y += __shfl_xor(acc0.y, 32);
    acc0.z += __shfl_xor(acc0.z, 32);
    acc0.w += __shfl_xor(acc0.w, 32);

    if (half == 0) {
        if (RELU) {
            acc0.x = fmaxf(acc0.x, 0.f); acc0.y = fmaxf(acc0.y, 0.f);
            acc0.z = fmaxf(acc0.z, 0.f); acc0.w = fmaxf(acc0.w, 0.f);
        }
        reinterpret_cast<float4*>(Out)[(size_t)node * 32 + l32] = acc0;
    }
}

// ---------------- readout: g = x[c]*x[c+1]; relu(g@W1+b1)@W2+b2 ----------------

__global__ __launch_bounds__(128) void readout_kernel(const float* __restrict__ X,
                                                      const int* __restrict__ center,
                                                      const float* __restrict__ w1,
                                                      const float* __restrict__ b1,
                                                      const float* __restrict__ w2,
                                                      const float* __restrict__ b2,
                                                      float* __restrict__ out, int n) {
    __shared__ float gv[H];
    __shared__ float red[H];
    int g = blockIdx.x;
    int c = threadIdx.x;
    int i0 = center[g];
    if (i0 > n - 1) i0 = n - 1;
    int i1 = (i0 + 1 < n) ? i0 + 1 : n - 1;
    gv[c] = X[(size_t)i0 * H + c] * X[(size_t)i1 * H + c];
    __syncthreads();
    float acc = b1[c];
    #pragma unroll 8
    for (int k = 0; k < H; ++k)
        acc = fmaf(gv[k], w1[k * H + c], acc);
    acc = fmaxf(acc, 0.f);
    red[c] = acc * w2[c];
    __syncthreads();
    for (int off = 64; off > 0; off >>= 1) {
        if (c < off) red[c] += red[c + off];
        __syncthreads();
    }
    if (c == 0) out[g] = red[0] + b2[0];
}

// ---------------- launcher ----------------

static inline size_t align_up(size_t x) { return (x + 255) & ~(size_t)255; }

extern "C" void kernel_launch(void* const* d_in, const int* in_sizes, int n_in,
                              void* d_out, int out_size, void* d_ws, size_t ws_size,
                              hipStream_t stream) {
    const int n = in_sizes[0];
    const int E = in_sizes[1] / 2;
    const int G = out_size;  // output is [G,1]

    const int*   z      = (const int*)d_in[0];
    const int*   ei     = (const int*)d_in[1];
    const int*   batch  = (const int*)d_in[2];
    const float* emb    = (const float*)d_in[4];
    const float* w0     = (const float*)d_in[5];
    const float* b0     = (const float*)d_in[6];
    const float* w1     = (const float*)d_in[7];
    const float* b1     = (const float*)d_in[8];
    const float* w2     = (const float*)d_in[9];
    const float* b2     = (const float*)d_in[10];
    const float* lin1_w = (const float*)d_in[11];
    const float* lin1_b = (const float*)d_in[12];
    const float* lin2_w = (const float*)d_in[13];
    const float* lin2_b = (const float*)d_in[14];

    const int* e_src = ei;
    const int* e_dst = ei + E;

    const int nPart = (n + SCAN_CHUNK - 1) / SCAN_CHUNK;  // 25 for n=50000 (<=64 required)

    char* p = (char*)d_ws;
    int*      cnt      = (int*)p;      p += align_up((size_t)n * 4);
    int*      row_ptr  = (int*)p;      p += align_up((size_t)(n + 1) * 4);
    int*      fill     = (int*)p;      p += align_up((size_t)n * 4);
    int*      center   = (int*)p;      p += align_up((size_t)G * 4);
    int*      partials = (int*)p;      p += align_up((size_t)64 * 4);
    int2*     csr_rec  = (int2*)p;     p += align_up((size_t)E * 8);
    float*    dinv     = (float*)p;    p += align_up((size_t)n * 4);
    unsigned* hB       = (unsigned*)p; p += align_up((size_t)n * 64 * 4);  // bf16-packed h
    float*    bufA     = (float*)p;    p += align_up((size_t)n * H * 4);

    const int TB = 256;
    dim3 gN((n + TB - 1) / TB);
    dim3 gE((E + TB - 1) / TB);
    dim3 gG((G + TB - 1) / TB);

    // build degree / dinv / CSR
    set_int_kernel<<<gN, TB, 0, stream>>>(cnt, n, 0);
    set_int_kernel<<<gN, TB, 0, stream>>>(fill, n, 0);
    set_int_kernel<<<gG, TB, 0, stream>>>(center, G, 0x7fffffff);
    count_kernel<<<gE, TB, 0, stream>>>(e_dst, E, cnt);
    scan_local<<<nPart, 256, 0, stream>>>(cnt, row_ptr, partials, dinv, n);
    scan_partials<<<1, 64, 0, stream>>>(partials, row_ptr, nPart, n);
    scan_add<<<gN, TB, 0, stream>>>(row_ptr, partials, n);
    fill_kernel<<<gE, TB, 0, stream>>>(e_src, e_dst, E, row_ptr, fill, dinv, csr_rec);
    center_kernel<<<gN, TB, 0, stream>>>(batch, n, center);

    dim3 gemm_grid((n + 63) / 64, 2);
    dim3 agg_grid((n + 3) / 4);

    // layer 0 (embedding gather fused into GEMM staging)
    gemm_kernel<true><<<gemm_grid, 256, 0, stream>>>(emb, z, w0, hB, n);
    agg_kernel<true><<<agg_grid, 256, 0, stream>>>(hB, row_ptr, csr_rec, dinv, b0, bufA, n);
    // layer 1
    gemm_kernel<false><<<gemm_grid, 256, 0, stream>>>(bufA, nullptr, w1, hB, n);
    agg_kernel<true><<<agg_grid, 256, 0, stream>>>(hB, row_ptr, csr_rec, dinv, b1, bufA, n);
    // layer 2 (no relu)
    gemm_kernel<false><<<gemm_grid, 256, 0, stream>>>(bufA, nullptr, w2, hB, n);
    agg_kernel<false><<<agg_grid, 256, 0, stream>>>(hB, row_ptr, csr_rec, dinv, b2, bufA, n);

    // readout
    readout_kernel<<<G, 128, 0, stream>>>(bufA, center, lin1_w, lin1_b, lin2_w, lin2_b,
                                          (float*)d_out, n);
}

// Round 11
// 280.687 us; speedup vs baseline: 8.2294x; 1.2109x over previous
//
#include <hip/hip_runtime.h>
#include <hip/hip_fp16.h>
#include <cstdint>
#include <cstddef>

#define H 128
#define SCAN_CHUNK 2048   // elements per scan_local block (256 thr x 8)

typedef _Float16 f16x8 __attribute__((ext_vector_type(8)));
typedef float f32x4 __attribute__((ext_vector_type(4)));

__device__ inline float2 up2(unsigned u) {
    return __half22float2(*reinterpret_cast<const __half2*>(&u));
}

// ---------------- utility kernels ----------------

__global__ void set_int_kernel(int* __restrict__ p, int n, int val) {
    int i = blockIdx.x * blockDim.x + threadIdx.x;
    if (i < n) p[i] = val;
}

__global__ void count_kernel(const int* __restrict__ dst, int E, int* __restrict__ cnt) {
    int e = blockIdx.x * blockDim.x + threadIdx.x;
    if (e < E) atomicAdd(&cnt[dst[e]], 1);
}

// convert 3 weight matrices fp32 [k][c] -> fp16 transposed Wt[m][c][k]
__global__ void wcvt_kernel(const float* __restrict__ w0, const float* __restrict__ w1,
                            const float* __restrict__ w2, _Float16* __restrict__ wt) {
    int idx = blockIdx.x * 256 + threadIdx.x;
    if (idx >= 3 * H * H) return;
    int m = idx >> 14;
    int c = (idx >> 7) & 127;   // output col (row of Wt)
    int k = idx & 127;          // k (inner dim of Wt)
    const float* W = (m == 0) ? w0 : (m == 1) ? w1 : w2;
    wt[idx] = (_Float16)W[k * H + c];
}

// per-block exclusive scan of cnt into row_ptr; block totals -> partials.
// Also computes dinv[i] = rsqrt(cnt[i]+1) (self-loop degree) for free.
__global__ __launch_bounds__(256) void scan_local(const int* __restrict__ cnt,
                                                  int* __restrict__ row_ptr,
                                                  int* __restrict__ partials,
                                                  float* __restrict__ dinv, int n) {
    __shared__ int sm[256];
    int tid = threadIdx.x;
    int base = blockIdx.x * SCAN_CHUNK + tid * 8;
    int v[8];
    int s = 0;
    #pragma unroll
    for (int j = 0; j < 8; ++j) {
        int i = base + j;
        v[j] = (i < n) ? cnt[i] : 0;
        if (i < n) dinv[i] = rsqrtf((float)(v[j] + 1));
        s += v[j];
    }
    sm[tid] = s;
    __syncthreads();
    #pragma unroll
    for (int off = 1; off < 256; off <<= 1) {
        int t = (tid >= off) ? sm[tid - off] : 0;
        __syncthreads();
        sm[tid] += t;
        __syncthreads();
    }
    int excl = sm[tid] - s;   // exclusive prefix within block
    if (tid == 255) partials[blockIdx.x] = sm[255];
    #pragma unroll
    for (int j = 0; j < 8; ++j) {
        int i = base + j;
        if (i < n) row_ptr[i] = excl;
        excl += v[j];
    }
}

// single-wave scan of block partials (nPart <= 64); writes row_ptr[n] = total.
__global__ __launch_bounds__(64) void scan_partials(int* __restrict__ partials,
                                                    int* __restrict__ row_ptr,
                                                    int nPart, int n) {
    int tid = threadIdx.x;
    int v = (tid < nPart) ? partials[tid] : 0;
    int ps = v;
    #pragma unroll
    for (int off = 1; off < 64; off <<= 1) {
        int t = __shfl_up(ps, off);
        if (tid >= off) ps += t;
    }
    if (tid < nPart) partials[tid] = ps - v;  // exclusive
    if (tid == 63) row_ptr[n] = ps;           // total edge count
}

__global__ void scan_add(int* __restrict__ row_ptr, const int* __restrict__ partials, int n) {
    int i = blockIdx.x * blockDim.x + threadIdx.x;
    if (i < n) row_ptr[i] += partials[i / SCAN_CHUNK];
}

// writes packed edge records: {src_idx, bitcast(norm)} per edge, CSR-ordered by dst
__global__ void fill_kernel(const int* __restrict__ src, const int* __restrict__ dst, int E,
                            const int* __restrict__ row_ptr, int* __restrict__ fill,
                            const float* __restrict__ dinv,
                            int2* __restrict__ csr_rec) {
    int e = blockIdx.x * blockDim.x + threadIdx.x;
    if (e < E) {
        int s = src[e], d = dst[e];
        int pos = atomicAdd(&fill[d], 1);
        int idx = row_ptr[d] + pos;
        float nm = dinv[s] * dinv[d];
        csr_rec[idx] = make_int2(s, __float_as_int(nm));
    }
}

__global__ void center_kernel(const int* __restrict__ batch, int n, int* __restrict__ center) {
    int i = blockIdx.x * blockDim.x + threadIdx.x;
    if (i < n) atomicMin(&center[batch[i]], i);
}

// ---------------- MFMA fp16 GEMM: Yh[n,128](fp16) = X[n,128](fp32) @ W[128,128] ----------------
// BM=64, 4 waves, each wave 16 rows x 128 cols (8 C-tiles of 16x16, K=128 in 4 steps of 32).
// Wt is fp16 transposed [col][k]; staged in LDS with XOR swizzle (addr ^= (col&7)<<4)
// to kill the 256B-row-stride bank conflict on ds_read_b128 b-frags.
// A-frags: read 8 fp32 from global (4 lanes cover a row's 128B contiguously), cvt to fp16.
// Epilogue: transpose C through per-wave private LDS, emit coalesced 64B chunks.
// Fragment layouts (m89-verified): A row=l&15,k=(l>>4)*8+e; B col=l&15,same k;
// C col=l&15,row=(l>>4)*4+reg.

template<bool GATHER>
__global__ __launch_bounds__(256) void gemm_mfma(const float* __restrict__ X,
                                                 const int* __restrict__ z,
                                                 const _Float16* __restrict__ Wt,
                                                 unsigned* __restrict__ Yh, int n) {
    __shared__ _Float16 Wl[H * H];    // 32 KB, swizzled
    __shared__ _Float16 Cl[64 * H];   // 16 KB transpose buffer (4KB per wave)
    int tid = threadIdx.x;

    // stage Wt -> Wl (2048 x 16B chunks), swizzled
    {
        const uint4* src = reinterpret_cast<const uint4*>(Wt);
        #pragma unroll
        for (int it = 0; it < 8; ++it) {
            int idx = it * 256 + tid;
            int c = idx >> 4, s = idx & 15;
            unsigned boff = (unsigned)(c * 256 + s * 16) ^ ((unsigned)(c & 7) << 4);
            *reinterpret_cast<uint4*>(reinterpret_cast<char*>(Wl) + boff) = src[idx];
        }
    }

    int m0 = blockIdx.x * 64;
    int wid = tid >> 6, lane = tid & 63;
    int l15 = lane & 15, lhi = lane >> 4;   // lhi in 0..3
    int grow = m0 + wid * 16 + l15;
    bool rowok = grow < n;
    const float* xrow;
    if (GATHER) {
        int zr = rowok ? z[grow] : 0;
        xrow = X + (size_t)zr * H;
    } else {
        xrow = X + (size_t)(rowok ? grow : 0) * H;
    }

    // per-lane raw LDS offsets for b-frags (swizzle applied after adding k offset)
    unsigned braw[8];
    unsigned swz = (unsigned)(l15 & 7) << 4;
    #pragma unroll
    for (int ct = 0; ct < 8; ++ct) {
        int c = ct * 16 + l15;
        braw[ct] = (unsigned)(c * 256 + lhi * 16);
    }

    f32x4 acc[8];
    #pragma unroll
    for (int ct = 0; ct < 8; ++ct) acc[ct] = (f32x4){0.f, 0.f, 0.f, 0.f};

    __syncthreads();

    #pragma unroll
    for (int kb = 0; kb < 4; ++kb) {
        const float* ap = xrow + kb * 32 + lhi * 8;
        float4 x0 = *reinterpret_cast<const float4*>(ap);
        float4 x1 = *reinterpret_cast<const float4*>(ap + 4);
        f16x8 a;
        a[0] = (_Float16)x0.x; a[1] = (_Float16)x0.y;
        a[2] = (_Float16)x0.z; a[3] = (_Float16)x0.w;
        a[4] = (_Float16)x1.x; a[5] = (_Float16)x1.y;
        a[6] = (_Float16)x1.z; a[7] = (_Float16)x1.w;
        #pragma unroll
        for (int ct = 0; ct < 8; ++ct) {
            unsigned boff = (braw[ct] + (unsigned)(kb * 64)) ^ swz;
            f16x8 b = *reinterpret_cast<const f16x8*>(
                reinterpret_cast<const char*>(Wl) + boff);
            acc[ct] = __builtin_amdgcn_mfma_f32_16x16x32_f16(a, b, acc[ct], 0, 0, 0);
        }
    }

    // epilogue: per-wave private transpose region (no cross-wave sharing -> no barrier)
    _Float16* cw = Cl + wid * 16 * H;
    #pragma unroll
    for (int ct = 0; ct < 8; ++ct) {
        #pragma unroll
        for (int r = 0; r < 4; ++r) {
            int row = lhi * 4 + r;
            int col = ct * 16 + l15;
            cw[row * H + col] = (_Float16)acc[ct][r];
        }
    }
    // write out: lane covers 64B: row = lane>>2, seg = lane&3
    int orow = lane >> 2, oseg = lane & 3;
    int growo = m0 + wid * 16 + orow;
    if (growo < n) {
        const uint4* cp = reinterpret_cast<const uint4*>(
            reinterpret_cast<const char*>(cw) + orow * 256 + oseg * 64);
        uint4* dp = reinterpret_cast<uint4*>(
            reinterpret_cast<char*>(Yh) + (size_t)growo * 256 + oseg * 64);
        dp[0] = cp[0]; dp[1] = cp[1]; dp[2] = cp[2]; dp[3] = cp[3];
    }
}

// ---------------- aggregation: Out[i] = b + sum_in h[src]*norm + h[i]*dinv^2 ----------------
// h is fp16-packed [n][128] (64 uints/row). One 64-lane wave per node:
// lanes 0-31 even edges, 32-63 odd edges; lane covers cols [4*l32, 4*l32+4)
// as one uint2 (8B). 4-stream unroll -> 8 independent 256B gathers in flight.
// Accumulation in fp32; output written fp32.

template<bool RELU>
__global__ __launch_bounds__(256) void agg_kernel(const unsigned* __restrict__ Hb,
                                                  const int* __restrict__ row_ptr,
                                                  const int2* __restrict__ csr_rec,
                                                  const float* __restrict__ dinv,
                                                  const float* __restrict__ bias,
                                                  float* __restrict__ Out, int n) {
    int node = blockIdx.x * 4 + (threadIdx.x >> 6);
    if (node >= n) return;
    int lane = threadIdx.x & 63;
    int half = lane >> 5;       // 0: even edges, 1: odd edges
    int l32  = lane & 31;
    const uint2* Hu = reinterpret_cast<const uint2*>(Hb);

    float4 acc0 = make_float4(0.f, 0.f, 0.f, 0.f);
    float4 acc1 = make_float4(0.f, 0.f, 0.f, 0.f);
    float4 acc2 = make_float4(0.f, 0.f, 0.f, 0.f);
    float4 acc3 = make_float4(0.f, 0.f, 0.f, 0.f);
    if (half == 0) {  // self term + bias, added once
        float di = dinv[node];
        float s = di * di;
        uint2 u = Hu[(size_t)node * 32 + l32];
        float4 bv = reinterpret_cast<const float4*>(bias)[l32];
        float2 f0 = up2(u.x), f1 = up2(u.y);
        acc0.x = bv.x + f0.x * s;
        acc0.y = bv.y + f0.y * s;
        acc0.z = bv.z + f1.x * s;
        acc0.w = bv.w + f1.y * s;
    }

    int beg = row_ptr[node], end = row_ptr[node + 1];
    int j = beg + half;
    // 4-stream main loop: edges j, j+2, j+4, j+6 gathered concurrently
    for (; j + 6 < end; j += 8) {
        int2 r0 = csr_rec[j];
        int2 r1 = csr_rec[j + 2];
        int2 r2 = csr_rec[j + 4];
        int2 r3 = csr_rec[j + 6];
        uint2 u0 = Hu[(size_t)r0.x * 32 + l32];
        uint2 u1 = Hu[(size_t)r1.x * 32 + l32];
        uint2 u2 = Hu[(size_t)r2.x * 32 + l32];
        uint2 u3 = Hu[(size_t)r3.x * 32 + l32];
        float n0 = __int_as_float(r0.y);
        float n1 = __int_as_float(r1.y);
        float n2 = __int_as_float(r2.y);
        float n3 = __int_as_float(r3.y);
        float2 a0 = up2(u0.x), b0 = up2(u0.y);
        float2 a1 = up2(u1.x), b1 = up2(u1.y);
        float2 a2 = up2(u2.x), b2 = up2(u2.y);
        float2 a3 = up2(u3.x), b3 = up2(u3.y);
        acc0.x = fmaf(a0.x, n0, acc0.x); acc0.y = fmaf(a0.y, n0, acc0.y);
        acc0.z = fmaf(b0.x, n0, acc0.z); acc0.w = fmaf(b0.y, n0, acc0.w);
        acc1.x = fmaf(a1.x, n1, acc1.x); acc1.y = fmaf(a1.y, n1, acc1.y);
        acc1.z = fmaf(b1.x, n1, acc1.z); acc1.w = fmaf(b1.y, n1, acc1.w);
        acc2.x = fmaf(a2.x, n2, acc2.x); acc2.y = fmaf(a2.y, n2, acc2.y);
        acc2.z = fmaf(b2.x, n2, acc2.z); acc2.w = fmaf(b2.y, n2, acc2.w);
        acc3.x = fmaf(a3.x, n3, acc3.x); acc3.y = fmaf(a3.y, n3, acc3.y);
        acc3.z = fmaf(b3.x, n3, acc3.z); acc3.w = fmaf(b3.y, n3, acc3.w);
    }
    // tail
    for (; j < end; j += 2) {
        int2 r0 = csr_rec[j];
        float n0 = __int_as_float(r0.y);
        uint2 u0 = Hu[(size_t)r0.x * 32 + l32];
        float2 a0 = up2(u0.x), b0 = up2(u0.y);
        acc0.x = fmaf(a0.x, n0, acc0.x); acc0.y = fmaf(a0.y, n0, acc0.y);
        acc0.z = fmaf(b0.x, n0, acc0.z); acc0.w = fmaf(b0.y, n0, acc0.w);
    }
    acc0.x += acc1.x + acc2.x + acc3.x;
    acc0.y += acc1.y + acc2.y + acc3.y;
    acc0.z += acc1.z + acc2.z + acc3.z;
    acc0.w += acc1.w + acc2.w + acc3.w;

    // combine the two halves (lane i gets lane i^32's partial)
    acc0.x += __shfl_xor(acc0.x, 32);
    acc0.y += __shfl_xor(acc0.y, 32);
    acc0.z += __shfl_xor(acc0.z, 32);
    acc0.w += __shfl_xor(acc0.w, 32);

    if (half == 0) {
        if (RELU) {
            acc0.x = fmaxf(acc0.x, 0.f); acc0.y = fmaxf(acc0.y, 0.f);
            acc0.z = fmaxf(acc0.z, 0.f); acc0.w = fmaxf(acc0.w, 0.f);
        }
        reinterpret_cast<float4*>(Out)[(size_t)node * 32 + l32] = acc0;
    }
}

// ---------------- readout: g = x[c]*x[c+1]; relu(g@W1+b1)@W2+b2 ----------------

__global__ __launch_bounds__(128) void readout_kernel(const float* __restrict__ X,
                                                      const int* __restrict__ center,
                                                      const float* __restrict__ w1,
                                                      const float* __restrict__ b1,
                                                      const float* __restrict__ w2,
                                                      const float* __restrict__ b2,
                                                      float* __restrict__ out, int n) {
    __shared__ float gv[H];
    __shared__ float red[H];
    int g = blockIdx.x;
    int c = threadIdx.x;
    int i0 = center[g];
    if (i0 > n - 1) i0 = n - 1;
    int i1 = (i0 + 1 < n) ? i0 + 1 : n - 1;
    gv[c] = X[(size_t)i0 * H + c] * X[(size_t)i1 * H + c];
    __syncthreads();
    float acc = b1[c];
    #pragma unroll 8
    for (int k = 0; k < H; ++k)
        acc = fmaf(gv[k], w1[k * H + c], acc);
    acc = fmaxf(acc, 0.f);
    red[c] = acc * w2[c];
    __syncthreads();
    for (int off = 64; off > 0; off >>= 1) {
        if (c < off) red[c] += red[c + off];
        __syncthreads();
    }
    if (c == 0) out[g] = red[0] + b2[0];
}

// ---------------- launcher ----------------

static inline size_t align_up(size_t x) { return (x + 255) & ~(size_t)255; }

extern "C" void kernel_launch(void* const* d_in, const int* in_sizes, int n_in,
                              void* d_out, int out_size, void* d_ws, size_t ws_size,
                              hipStream_t stream) {
    const int n = in_sizes[0];
    const int E = in_sizes[1] / 2;
    const int G = out_size;  // output is [G,1]

    const int*   z      = (const int*)d_in[0];
    const int*   ei     = (const int*)d_in[1];
    const int*   batch  = (const int*)d_in[2];
    const float* emb    = (const float*)d_in[4];
    const float* w0     = (const float*)d_in[5];
    const float* b0     = (const float*)d_in[6];
    const float* w1     = (const float*)d_in[7];
    const float* b1     = (const float*)d_in[8];
    const float* w2     = (const float*)d_in[9];
    const float* b2     = (const float*)d_in[10];
    const float* lin1_w = (const float*)d_in[11];
    const float* lin1_b = (const float*)d_in[12];
    const float* lin2_w = (const float*)d_in[13];
    const float* lin2_b = (const float*)d_in[14];

    const int* e_src = ei;
    const int* e_dst = ei + E;

    const int nPart = (n + SCAN_CHUNK - 1) / SCAN_CHUNK;  // 25 for n=50000 (<=64 required)

    char* p = (char*)d_ws;
    int*       cnt      = (int*)p;       p += align_up((size_t)n * 4);
    int*       row_ptr  = (int*)p;       p += align_up((size_t)(n + 1) * 4);
    int*       fill     = (int*)p;       p += align_up((size_t)n * 4);
    int*       center   = (int*)p;       p += align_up((size_t)G * 4);
    int*       partials = (int*)p;       p += align_up((size_t)64 * 4);
    int2*      csr_rec  = (int2*)p;      p += align_up((size_t)E * 8);
    float*     dinv     = (float*)p;     p += align_up((size_t)n * 4);
    _Float16*  wt       = (_Float16*)p;  p += align_up((size_t)3 * H * H * 2);
    unsigned*  hB       = (unsigned*)p;  p += align_up((size_t)n * 64 * 4);  // fp16-packed h
    float*     bufA     = (float*)p;     p += align_up((size_t)n * H * 4);

    const int TB = 256;
    dim3 gN((n + TB - 1) / TB);
    dim3 gE((E + TB - 1) / TB);
    dim3 gG((G + TB - 1) / TB);

    // build degree / dinv / CSR; convert weights
    set_int_kernel<<<gN, TB, 0, stream>>>(cnt, n, 0);
    set_int_kernel<<<gN, TB, 0, stream>>>(fill, n, 0);
    set_int_kernel<<<gG, TB, 0, stream>>>(center, G, 0x7fffffff);
    wcvt_kernel<<<(3 * H * H + 255) / 256, 256, 0, stream>>>(w0, w1, w2, wt);
    count_kernel<<<gE, TB, 0, stream>>>(e_dst, E, cnt);
    scan_local<<<nPart, 256, 0, stream>>>(cnt, row_ptr, partials, dinv, n);
    scan_partials<<<1, 64, 0, stream>>>(partials, row_ptr, nPart, n);
    scan_add<<<gN, TB, 0, stream>>>(row_ptr, partials, n);
    fill_kernel<<<gE, TB, 0, stream>>>(e_src, e_dst, E, row_ptr, fill, dinv, csr_rec);
    center_kernel<<<gN, TB, 0, stream>>>(batch, n, center);

    dim3 gemm_grid((n + 63) / 64);
    dim3 agg_grid((n + 3) / 4);

    // layer 0 (embedding gather fused into GEMM A-frag load)
    gemm_mfma<true><<<gemm_grid, 256, 0, stream>>>(emb, z, wt, hB, n);
    agg_kernel<true><<<agg_grid, 256, 0, stream>>>(hB, row_ptr, csr_rec, dinv, b0, bufA, n);
    // layer 1
    gemm_mfma<false><<<gemm_grid, 256, 0, stream>>>(bufA, nullptr, wt + H * H, hB, n);
    agg_kernel<true><<<agg_grid, 256, 0, stream>>>(hB, row_ptr, csr_rec, dinv, b1, bufA, n);
    // layer 2 (no relu)
    gemm_mfma<false><<<gemm_grid, 256, 0, stream>>>(bufA, nullptr, wt + 2 * H * H, hB, n);
    agg_kernel<false><<<agg_grid, 256, 0, stream>>>(hB, row_ptr, csr_rec, dinv, b2, bufA, n);

    // readout
    readout_kernel<<<G, 128, 0, stream>>>(bufA, center, lin1_w, lin1_b, lin2_w, lin2_b,
                                          (float*)d_out, n);
}